// Round 1
// baseline (2840.778 us; speedup 1.0000x reference)
//
#include <hip/hip_runtime.h>
#include <math.h>

// Problem constants: B=256, H=16 -> G=4096 groups; N=256, D=64, L=64 landmarks.
#define G_TOT 4096
#define TPB 256
#define STR 66               // padded LDS row stride (floats)
#define BUFN (64 * STR)      // one 64x66 buffer = 4224 floats
#define SMEM_BYTES (9 * BUFN * 4)  // 152064 bytes dynamic LDS for k_main

__device__ __forceinline__ float activ_f(float x) {
    // exp(min(x,5)) + relu(x-5)
    return expf(fminf(x, 5.0f)) + fmaxf(x - 5.0f, 0.0f);
}

// acc[i][j] += sum_k AT[k][4*tr+i] * B[k][4*tc+j]
// AT is the transposed A operand ([k][r] layout), B row-major ([k][c]).
__device__ __forceinline__ void mm64(const float* __restrict__ AT,
                                     const float* __restrict__ Bm,
                                     float acc[4][4], int tr, int tc) {
    const float* at = AT + (tr << 2);
    const float* bp = Bm + (tc << 2);
#pragma unroll 4
    for (int kk = 0; kk < 64; ++kk) {
        const float a0 = at[0], a1 = at[1], a2 = at[2], a3 = at[3];
        const float b0 = bp[0], b1 = bp[1], b2 = bp[2], b3 = bp[3];
        acc[0][0] = fmaf(a0, b0, acc[0][0]); acc[0][1] = fmaf(a0, b1, acc[0][1]);
        acc[0][2] = fmaf(a0, b2, acc[0][2]); acc[0][3] = fmaf(a0, b3, acc[0][3]);
        acc[1][0] = fmaf(a1, b0, acc[1][0]); acc[1][1] = fmaf(a1, b1, acc[1][1]);
        acc[1][2] = fmaf(a1, b2, acc[1][2]); acc[1][3] = fmaf(a1, b3, acc[1][3]);
        acc[2][0] = fmaf(a2, b0, acc[2][0]); acc[2][1] = fmaf(a2, b1, acc[2][1]);
        acc[2][2] = fmaf(a2, b2, acc[2][2]); acc[2][3] = fmaf(a2, b3, acc[2][3]);
        acc[3][0] = fmaf(a3, b0, acc[3][0]); acc[3][1] = fmaf(a3, b1, acc[3][1]);
        acc[3][2] = fmaf(a3, b2, acc[3][2]); acc[3][3] = fmaf(a3, b3, acc[3][3]);
        at += STR; bp += STR;
    }
}

// Stage 64 rows x 64 cols from global (row stride 64) into LDS [64][STR], row-major.
__device__ __forceinline__ void stage_rows(const float* __restrict__ src,
                                           float* __restrict__ dst, int t) {
    const float4* s4 = reinterpret_cast<const float4*>(src);
#pragma unroll
    for (int i = 0; i < 4; ++i) {
        const int f = i * 256 + t;          // float4 index, 16 per row
        const int r = f >> 4, c4 = (f & 15) << 2;
        const float4 vv = s4[f];
        float* d = dst + r * STR + c4;
        d[0] = vv.x; d[1] = vv.y; d[2] = vv.z; d[3] = vv.w;
    }
}

// Stage transposed: dst[d][n] = src[n][d]
__device__ __forceinline__ void stage_rows_T(const float* __restrict__ src,
                                             float* __restrict__ dst, int t) {
    const float4* s4 = reinterpret_cast<const float4*>(src);
#pragma unroll
    for (int i = 0; i < 4; ++i) {
        const int f = i * 256 + t;
        const int r = f >> 4, c4 = (f & 15) << 2;
        const float4 vv = s4[f];
        dst[(c4 + 0) * STR + r] = vv.x;
        dst[(c4 + 1) * STR + r] = vv.y;
        dst[(c4 + 2) * STR + r] = vv.z;
        dst[(c4 + 3) * STR + r] = vv.w;
    }
}

// Pool one staged 64-row tile (tile index tt) into the transposed landmark
// buffer MT[d][l]:  MT[d][16*tt+ll] = mean of 4 rows {rb,rb+1,rb+16,rb+17}.
__device__ __forceinline__ void pool_tile(const float* __restrict__ tile,
                                          float* __restrict__ MT, int tt, int t) {
    const int ll = t >> 4;                 // local landmark 0..15
    const int d0 = (t & 15) << 2;          // 4 consecutive d per thread
    const int rb = ((ll >> 3) << 5) + ((ll & 7) << 1);
#pragma unroll
    for (int jd = 0; jd < 4; ++jd) {
        const int d = d0 + jd;
        const float s = tile[rb * STR + d] + tile[(rb + 1) * STR + d] +
                        tile[(rb + 16) * STR + d] + tile[(rb + 17) * STR + d];
        MT[d * STR + (tt * 16 + ll)] = 0.25f * s;
    }
}

__global__ void k_init(float* ws) {
    if (threadIdx.x < 2) ws[threadIdx.x] = 0.0f;
}

// Kernel 1: per group, pool q_m/k_m, temp = activ(q_m k_m^T), global max of
// row sums (ws[0]) and col sums (ws[1]) via float-as-int atomicMax (values > 0).
__global__ __launch_bounds__(TPB) void k_reduce(const float* __restrict__ q,
                                                const float* __restrict__ k,
                                                float* __restrict__ ws) {
    __shared__ float QMT[BUFN];
    __shared__ float KMT[BUFN];
    __shared__ float XT[BUFN];
    const int t = threadIdx.x, g = blockIdx.x;
    const int tr = t >> 4, tc = t & 15;
    const float* qg = q + (size_t)g * 16384;
    const float* kg = k + (size_t)g * 16384;

    for (int tt = 0; tt < 4; ++tt) {
        stage_rows(qg + tt * 4096, XT, t); __syncthreads();
        pool_tile(XT, QMT, tt, t);         __syncthreads();
    }
    for (int tt = 0; tt < 4; ++tt) {
        stage_rows(kg + tt * 4096, XT, t); __syncthreads();
        pool_tile(XT, KMT, tt, t);         __syncthreads();
    }

    float acc[4][4] = {};
    mm64(QMT, KMT, acc, tr, tc);
#pragma unroll
    for (int i = 0; i < 4; ++i)
#pragma unroll
        for (int j = 0; j < 4; ++j)
            XT[((tc << 2) + j) * STR + (tr << 2) + i] = activ_f(acc[i][j]);  // XT[m][l]
    __syncthreads();

    if (t < 64) {
        // row sum of X for row l=t : sum_m X[l][m] = sum_m XT[m][l]
        float rs = 0.0f;
        for (int m = 0; m < 64; ++m) rs += XT[m * STR + t];
        for (int off = 32; off; off >>= 1) rs = fmaxf(rs, __shfl_down(rs, off));
        if (t == 0) atomicMax((int*)ws, __float_as_int(rs));
    } else if (t < 128) {
        // col sum of X for col m=t-64 : sum_l X[l][m] = sum_l XT[m][l]
        const int m = t - 64;
        float cs = 0.0f;
        const float* xr = XT + m * STR;
        for (int l = 0; l < 64; ++l) cs += xr[l];
        for (int off = 32; off; off >>= 1) cs = fmaxf(cs, __shfl_down(cs, off));
        if (t == 64) atomicMax(((int*)ws) + 1, __float_as_int(cs));
    }
}

// Kernel 2: per group, everything else fused.
__global__ __launch_bounds__(TPB) void k_main(const float* __restrict__ q,
                                              const float* __restrict__ k,
                                              const float* __restrict__ v,
                                              const float* __restrict__ ws,
                                              float* __restrict__ out) {
    extern __shared__ float sm[];
    float* QMT = sm;                 // [d][l]
    float* KMT = sm + BUFN;          // [d][m]
    float* XTb = sm + 2 * BUFN;      // X^T ([m][l]); becomes KV in phase E
    float* B0  = sm + 3 * BUFN;      // Z (row-major), stays in place
    float* B1  = sm + 4 * BUFN;
    float* B2  = sm + 5 * BUFN;
    float* B3  = sm + 6 * BUFN;
    float* B4  = sm + 7 * BUFN;
    float* B5  = sm + 8 * BUFN;
    const int t = threadIdx.x, g = blockIdx.x;
    const int tr = t >> 4, tc = t & 15;
    const int r0 = tr << 2, c0 = tc << 2;
    const float* qg = q + (size_t)g * 16384;
    const float* kg = k + (size_t)g * 16384;
    const float* vg = v + (size_t)g * 16384;
    float* og = out + (size_t)g * 16384;

    // Phase A: pooling (B0 as staging scratch)
    for (int tt = 0; tt < 4; ++tt) {
        stage_rows(qg + tt * 4096, B0, t); __syncthreads();
        pool_tile(B0, QMT, tt, t);         __syncthreads();
    }
    for (int tt = 0; tt < 4; ++tt) {
        stage_rows(kg + tt * 4096, B0, t); __syncthreads();
        pool_tile(B0, KMT, tt, t);         __syncthreads();
    }

    // Phase B: XT = (activ(QM @ KM^T))^T
    {
        float acc[4][4] = {};
        mm64(QMT, KMT, acc, tr, tc);
#pragma unroll
        for (int i = 0; i < 4; ++i)
#pragma unroll
            for (int j = 0; j < 4; ++j)
                XTb[(c0 + j) * STR + r0 + i] = activ_f(acc[i][j]);
    }
    __syncthreads();

    // Phase C: Z = s*X^T (row copy of XT), ZT = s*X (transpose of XT)
    const float scale = 1.0f / (ws[0] * ws[1] + 1e-15f);
    for (int idx = t; idx < BUFN; idx += TPB) B0[idx] = scale * XTb[idx];
#pragma unroll
    for (int i = 0; i < 4; ++i)
#pragma unroll
        for (int j = 0; j < 4; ++j)
            B1[(r0 + i) * STR + c0 + j] = scale * XTb[(c0 + j) * STR + r0 + i];
    __syncthreads();

    // Phase D: 6 Newton-Schulz iterations. z <- 0.25 z (13I -15M +7M^2 -M^3), M=xz
    float *pZ = B0, *pZT = B1, *bT1 = B2, *bT1T = B3, *bT2T = B4, *bT3 = B5;
    for (int it = 0; it < 6; ++it) {
        {   // M3: T1 = X @ Z   (AT = XT, B = Z) ; write T1 and T1^T
            float acc[4][4] = {};
            mm64(XTb, pZ, acc, tr, tc);
#pragma unroll
            for (int i = 0; i < 4; ++i)
#pragma unroll
                for (int j = 0; j < 4; ++j) {
                    bT1 [(r0 + i) * STR + c0 + j] = acc[i][j];
                    bT1T[(c0 + j) * STR + r0 + i] = acc[i][j];
                }
        }
        __syncthreads();
        {   // M4: T2 = T1 @ T1 ; keep transpose only
            float acc[4][4] = {};
            mm64(bT1T, bT1, acc, tr, tc);
#pragma unroll
            for (int i = 0; i < 4; ++i)
#pragma unroll
                for (int j = 0; j < 4; ++j)
                    bT2T[(c0 + j) * STR + r0 + i] = acc[i][j];
        }
        __syncthreads();
        {   // M5+M6: T3 = 0.25*(13I - 15*T1 + 7*T2 - T2@T1)
            float acc[4][4] = {};
            mm64(bT2T, bT1, acc, tr, tc);   // (T2@T1)[r][c]
#pragma unroll
            for (int i = 0; i < 4; ++i)
#pragma unroll
                for (int j = 0; j < 4; ++j) {
                    const int r = r0 + i, c = c0 + j;
                    const float t1rc = bT1[r * STR + c];
                    const float t2rc = bT2T[c * STR + r];
                    bT3[r * STR + c] =
                        0.25f * ((r == c ? 13.0f : 0.0f) - 15.0f * t1rc + 7.0f * t2rc - acc[i][j]);
                }
        }
        __syncthreads();
        {   // M7 (transposed form): Znew^T[r][c] = sum_k T3[k][r] * ZT[k][c]
            float acc[4][4] = {};
            mm64(bT3, pZT, acc, tr, tc);
#pragma unroll
            for (int i = 0; i < 4; ++i)
#pragma unroll
                for (int j = 0; j < 4; ++j) {
                    const int r = r0 + i, c = c0 + j;
                    pZ[c * STR + r] = acc[i][j];               // Znew in place (row-major)
                    if (it < 5) bT1T[r * STR + c] = acc[i][j]; // Znew^T row-major
                }
        }
        __syncthreads();
        if (it < 5) { float* tmp = pZT; pZT = bT1T; bT1T = tmp; }
    }
    // Final z (row-major) lives in B0 (pZ). Free scratch: B1..B5.
    float* F0 = B1; float* F1 = B2; float* F2 = B3;

    // Phase E: KV = activ(QM @ K^T) @ [V | 1]   (KV reuses XT buffer)
    float* KV = XTb;
    for (int idx = t; idx < BUFN; idx += TPB) KV[idx] = 0.0f;
    __syncthreads();
    for (int tt = 0; tt < 4; ++tt) {
        stage_rows_T(kg + tt * 4096, F0, t);   // ktT[d][n]
        stage_rows  (vg + tt * 4096, F1, t);   // v[n][e]
        __syncthreads();
        {   // sT[n][l] = activ( sum_d QM[l][d] * k[n][d] )
            float acc[4][4] = {};
            mm64(QMT, F0, acc, tr, tc);
#pragma unroll
            for (int i = 0; i < 4; ++i)
#pragma unroll
                for (int j = 0; j < 4; ++j)
                    F2[(c0 + j) * STR + r0 + i] = activ_f(acc[i][j]);
        }
        __syncthreads();
        {   // KV[l][e] += sum_n s[l][n] v[n][e]
            float acc[4][4] = {};
            mm64(F2, F1, acc, tr, tc);
#pragma unroll
            for (int i = 0; i < 4; ++i)
#pragma unroll
                for (int j = 0; j < 4; ++j)
                    KV[(r0 + i) * STR + c0 + j] += acc[i][j];
        }
        if (t < 64) {   // ones column
            float ssum = 0.0f;
            for (int n = 0; n < 64; ++n) ssum += F2[n * STR + t];
            KV[t * STR + 64] += ssum;
        }
        __syncthreads();
    }

    // Phase F: per 64-row tile of q: qk = activ(q @ KM^T); w = qk@Z; prod = w@KV; divide.
    for (int tt = 0; tt < 4; ++tt) {
        stage_rows_T(qg + tt * 4096, F0, t);   // qtT[d][n]
        __syncthreads();
        {   // qkT[l][n] = activ( sum_d q[n][d] KM[l][d] )
            float acc[4][4] = {};
            mm64(F0, KMT, acc, tr, tc);        // C[n][l]
#pragma unroll
            for (int i = 0; i < 4; ++i)
#pragma unroll
                for (int j = 0; j < 4; ++j)
                    F1[(c0 + j) * STR + r0 + i] = activ_f(acc[i][j]);
        }
        __syncthreads();
        {   // wT[c][n] : w = qk @ Z
            float acc[4][4] = {};
            mm64(F1, pZ, acc, tr, tc);         // C[n][c]
#pragma unroll
            for (int i = 0; i < 4; ++i)
#pragma unroll
                for (int j = 0; j < 4; ++j)
                    F2[(c0 + j) * STR + r0 + i] = acc[i][j];
        }
        __syncthreads();
        {   // prod = w @ KV (65 cols; col 64 folded into den), then divide
            float acc[4][4] = {};
            float den[4] = {};
            const float* at = F2 + r0;
            const float* bp = KV + c0;
            const float* kvp = KV + 64;
#pragma unroll 4
            for (int kk = 0; kk < 64; ++kk) {
                const float a0 = at[0], a1 = at[1], a2 = at[2], a3 = at[3];
                const float b0 = bp[0], b1 = bp[1], b2 = bp[2], b3 = bp[3];
                const float ko = *kvp;
                acc[0][0] = fmaf(a0, b0, acc[0][0]); acc[0][1] = fmaf(a0, b1, acc[0][1]);
                acc[0][2] = fmaf(a0, b2, acc[0][2]); acc[0][3] = fmaf(a0, b3, acc[0][3]);
                acc[1][0] = fmaf(a1, b0, acc[1][0]); acc[1][1] = fmaf(a1, b1, acc[1][1]);
                acc[1][2] = fmaf(a1, b2, acc[1][2]); acc[1][3] = fmaf(a1, b3, acc[1][3]);
                acc[2][0] = fmaf(a2, b0, acc[2][0]); acc[2][1] = fmaf(a2, b1, acc[2][1]);
                acc[2][2] = fmaf(a2, b2, acc[2][2]); acc[2][3] = fmaf(a2, b3, acc[2][3]);
                acc[3][0] = fmaf(a3, b0, acc[3][0]); acc[3][1] = fmaf(a3, b1, acc[3][1]);
                acc[3][2] = fmaf(a3, b2, acc[3][2]); acc[3][3] = fmaf(a3, b3, acc[3][3]);
                den[0] = fmaf(a0, ko, den[0]); den[1] = fmaf(a1, ko, den[1]);
                den[2] = fmaf(a2, ko, den[2]); den[3] = fmaf(a3, ko, den[3]);
                at += STR; bp += STR; kvp += STR;
            }
#pragma unroll
            for (int i = 0; i < 4; ++i) {
                const float inv = 1.0f / (den[i] + 1e-12f);
#pragma unroll
                for (int j = 0; j < 4; ++j)
                    F0[(r0 + i) * STR + c0 + j] = acc[i][j] * inv;  // F0 (qtT) dead, reuse
            }
        }
        __syncthreads();
        // coalesced store of the 64x64 output tile
#pragma unroll
        for (int i = 0; i < 4; ++i) {
            const int f = i * 256 + t;
            const int r = f >> 4, cc4 = (f & 15) << 2;
            float4 vv;
            vv.x = F0[r * STR + cc4 + 0];
            vv.y = F0[r * STR + cc4 + 1];
            vv.z = F0[r * STR + cc4 + 2];
            vv.w = F0[r * STR + cc4 + 3];
            *reinterpret_cast<float4*>(og + (tt * 64 + r) * 64 + cc4) = vv;
        }
        __syncthreads();
    }
}

extern "C" void kernel_launch(void* const* d_in, const int* in_sizes, int n_in,
                              void* d_out, int out_size, void* d_ws, size_t ws_size,
                              hipStream_t stream) {
    const float* q = (const float*)d_in[0];
    const float* k = (const float*)d_in[1];
    const float* v = (const float*)d_in[2];
    float* out = (float*)d_out;
    float* ws  = (float*)d_ws;

    (void)in_sizes; (void)n_in; (void)out_size; (void)ws_size;

    // Allow >64KB dynamic LDS (idempotent; not a stream op, capture-safe).
    hipFuncSetAttribute((const void*)k_main,
                        hipFuncAttributeMaxDynamicSharedMemorySize, SMEM_BYTES);

    k_init<<<1, 64, 0, stream>>>(ws);
    k_reduce<<<G_TOT, TPB, 0, stream>>>(q, k, ws);
    k_main<<<G_TOT, TPB, SMEM_BYTES, stream>>>(q, k, v, ws, out);
}

// Round 3
// 1726.998 us; speedup vs baseline: 1.6449x; 1.6449x over previous
//
#include <hip/hip_runtime.h>
#include <math.h>

// PnPNystra attention, MFMA rewrite v2 (f16 split planes).
// G=4096 groups (B*H), N=256, d=64, L=64.
// All 64x64 matrices in LDS as SPLIT f16: v ~= h + l/2048 (l stored pre-scaled
// by 2048 so it stays in f16 normal range -> denorm-flush-proof).
// Every matmul = v_mfma_f32_32x32x16_f16 x3 (hh, h*l, l*h), fp32 accumulate.
// Product error ~2^-21 * sum|terms| => fp32-grade logits into exp().
// Z (Newton-Schulz iterate) is globally tiny -> stored scaled by 1024.

#define G_TOT 4096
#define TPB 256
typedef _Float16 f16;
typedef __attribute__((ext_vector_type(8))) _Float16 f16x8;
typedef __attribute__((ext_vector_type(16))) float f32x16;

#define NPLANES 18
#define SMEM_BYTES (NPLANES * 4096 * 2 + 2 * 64 * 4)  // 147968 B

#define LSCALE 2048.0f
#define LINV   (1.0f / 2048.0f)
#define ZS     1024.0f
#define ZINV   (1.0f / 1024.0f)

struct HL { f16 h, l; };
__device__ __forceinline__ HL split2(float v) {
    HL r;
    r.h = (f16)v;
    r.l = (f16)((v - (float)r.h) * LSCALE);
    return r;
}
__device__ __forceinline__ float join2(f16 h, f16 l) {
    return (float)h + (float)l * LINV;
}
// swizzled element index into a 64x64 plane: row r, col c
__device__ __forceinline__ int swi(int r, int c) {
    return (r << 6) + (c ^ ((r & 7) << 3));
}
__device__ __forceinline__ float activ_f(float x) {
    return expf(fminf(x, 5.0f)) + fmaxf(x - 5.0f, 0.0f);
}
__device__ __forceinline__ void split_w(f16* Ph, f16* Pl, int r, int c, float v) {
    HL s = split2(v);
    const int o = swi(r, c);
    Ph[o] = s.h;
    Pl[o] = s.l;
}
__device__ __forceinline__ f32x16 fzero() {
    f32x16 z;
#pragma unroll
    for (int i = 0; i < 16; ++i) z[i] = 0.f;
    return z;
}

// 64x64x64 matmul, this wave's 32x32 quadrant (wr,wc), split-f16 3-term.
// A stored [m][k] planes, B stored [n][k] planes (i.e. B^T row-major).
// Result = accIn + A*B (with lo-plane descale folded in at the end).
__device__ __forceinline__ f32x16 mm64q(const f16* __restrict__ Ah, const f16* __restrict__ Al,
                                        const f16* __restrict__ Bh, const f16* __restrict__ Bl,
                                        int lane, int wr, int wc, f32x16 acc) {
    const int cl = lane & 31, hh = lane >> 5;
    const int ar = (wr << 5) + cl, br = (wc << 5) + cl;
    const int abase = ar << 6, axor = (ar & 7) << 3;
    const int bbase = br << 6, bxor = (br & 7) << 3;
    f32x16 ax1 = fzero();
    f32x16 ax2 = fzero();
#pragma unroll
    for (int ks = 0; ks < 4; ++ks) {
        const int k0 = (ks << 4) + (hh << 3);
        const int ao = abase + (k0 ^ axor);
        const int bo = bbase + (k0 ^ bxor);
        f16x8 a_h = *(const f16x8*)(Ah + ao);
        f16x8 a_l = *(const f16x8*)(Al + ao);
        f16x8 b_h = *(const f16x8*)(Bh + bo);
        f16x8 b_l = *(const f16x8*)(Bl + bo);
        acc = __builtin_amdgcn_mfma_f32_32x32x16_f16(a_h, b_h, acc, 0, 0, 0);
        ax1 = __builtin_amdgcn_mfma_f32_32x32x16_f16(a_h, b_l, ax1, 0, 0, 0);
        ax2 = __builtin_amdgcn_mfma_f32_32x32x16_f16(a_l, b_h, ax2, 0, 0, 0);
    }
    acc += (ax1 + ax2) * LINV;
    return acc;
}

// pool 2x2-mean landmarks straight from global fp32 [256][64] into split planes [64][64]
__device__ __forceinline__ void pool_global(const float* __restrict__ src,
                                            f16* Ph, f16* Pl, int t) {
    const int ll = t >> 4, d0 = (t & 15) << 2;
    const int rb = ((ll >> 3) << 5) + ((ll & 7) << 1);
#pragma unroll
    for (int tt = 0; tt < 4; ++tt) {
        const float* p = src + (size_t)((tt << 6) + rb) * 64 + d0;
        float4 a = *(const float4*)p;
        float4 b = *(const float4*)(p + 64);
        float4 c = *(const float4*)(p + 1024);
        float4 d = *(const float4*)(p + 1088);
        const int L = (tt << 4) + ll;
        split_w(Ph, Pl, L, d0 + 0, 0.25f * (a.x + b.x + c.x + d.x));
        split_w(Ph, Pl, L, d0 + 1, 0.25f * (a.y + b.y + c.y + d.y));
        split_w(Ph, Pl, L, d0 + 2, 0.25f * (a.z + b.z + c.z + d.z));
        split_w(Ph, Pl, L, d0 + 3, 0.25f * (a.w + b.w + c.w + d.w));
    }
}

// stage 64x64 fp32 global tile row-major into split planes
__device__ __forceinline__ void stage_rm(const float* __restrict__ src,
                                         f16* Ph, f16* Pl, int t) {
#pragma unroll
    for (int i = 0; i < 4; ++i) {
        const int f = i * 256 + t;
        const int r = f >> 4, c4 = (f & 15) << 2;
        float4 vv = *(const float4*)(src + (size_t)f * 4);
        split_w(Ph, Pl, r, c4 + 0, vv.x);
        split_w(Ph, Pl, r, c4 + 1, vv.y);
        split_w(Ph, Pl, r, c4 + 2, vv.z);
        split_w(Ph, Pl, r, c4 + 3, vv.w);
    }
}

// stage 64x64 fp32 global tile TRANSPOSED into split planes: plane[e][n] = src[n][e]
__device__ __forceinline__ void stage_t(const float* __restrict__ src,
                                        f16* Ph, f16* Pl, int t) {
#pragma unroll
    for (int i = 0; i < 4; ++i) {
        const int f = i * 256 + t;
        const int n = f >> 4, e0 = (f & 15) << 2;
        float4 vv = *(const float4*)(src + (size_t)f * 4);
        split_w(Ph, Pl, e0 + 0, n, vv.x);
        split_w(Ph, Pl, e0 + 1, n, vv.y);
        split_w(Ph, Pl, e0 + 2, n, vv.z);
        split_w(Ph, Pl, e0 + 3, n, vv.w);
    }
}

// pool landmarks of one staged K tile (tile tt) into KM planes
__device__ __forceinline__ void pool_lds(const f16* Kh, const f16* Kl,
                                         f16* Ph, f16* Pl, int t, int tt) {
    const int ll = t >> 4, d0 = (t & 15) << 2;
    const int rb = ((ll >> 3) << 5) + ((ll & 7) << 1);
    float s0 = 0, s1 = 0, s2 = 0, s3 = 0;
#pragma unroll
    for (int rr = 0; rr < 4; ++rr) {
        const int r = rb + (rr & 1) + ((rr >> 1) << 4);
        const int o0 = swi(r, d0), o1 = swi(r, d0 + 1), o2 = swi(r, d0 + 2), o3 = swi(r, d0 + 3);
        s0 += join2(Kh[o0], Kl[o0]);
        s1 += join2(Kh[o1], Kl[o1]);
        s2 += join2(Kh[o2], Kl[o2]);
        s3 += join2(Kh[o3], Kl[o3]);
    }
    const int L = (tt << 4) + ll;
    split_w(Ph, Pl, L, d0 + 0, 0.25f * s0);
    split_w(Ph, Pl, L, d0 + 1, 0.25f * s1);
    split_w(Ph, Pl, L, d0 + 2, 0.25f * s2);
    split_w(Ph, Pl, L, d0 + 3, 0.25f * s3);
}

#define FRAG_RC                                                        \
    const int R = (wr << 5) + (m & 3) + ((m >> 2) << 3) + (hh << 2);   \
    const int C = (wc << 5) + cl;

#define WAVE_SUM32(v)            \
    v += __shfl_xor(v, 1);       \
    v += __shfl_xor(v, 2);       \
    v += __shfl_xor(v, 4);       \
    v += __shfl_xor(v, 8);       \
    v += __shfl_xor(v, 16);

__global__ void k_init(float* ws) {
    if (threadIdx.x < 2) ws[threadIdx.x] = 0.0f;
}

// global max of row/col sums of activ(QM @ KM^T) over all groups
__global__ __launch_bounds__(TPB) void k_reduce(const float* __restrict__ q,
                                                const float* __restrict__ k,
                                                float* __restrict__ ws) {
    __shared__ f16 pls[4 * 4096];
    __shared__ float rowS[64], colS[64];
    const int t = threadIdx.x, g = blockIdx.x;
    const int lane = t & 63, wv = t >> 6, wr = wv >> 1, wc = wv & 1;
    const int cl = lane & 31, hh = lane >> 5;
    if (t < 64) rowS[t] = 0.f;
    else if (t < 128) colS[t - 64] = 0.f;
    pool_global(q + (size_t)g * 16384, pls, pls + 4096, t);
    pool_global(k + (size_t)g * 16384, pls + 8192, pls + 12288, t);
    __syncthreads();
    f32x16 a = mm64q(pls, pls + 4096, pls + 8192, pls + 12288, lane, wr, wc, fzero());
    float colp = 0.f;
#pragma unroll
    for (int m = 0; m < 16; ++m) {
        float x = activ_f(a[m]);
        const int R = (wr << 5) + (m & 3) + ((m >> 2) << 3) + (hh << 2);
        float vs = x;
        WAVE_SUM32(vs)
        if (cl == 0) atomicAdd(&rowS[R], vs);
        colp += x;
    }
    colp += __shfl_xor(colp, 32);
    if (hh == 0) atomicAdd(&colS[(wc << 5) + cl], colp);
    __syncthreads();
    if (t < 64) {
        float vmx = rowS[t];
        for (int off = 1; off < 64; off <<= 1) vmx = fmaxf(vmx, __shfl_xor(vmx, off));
        if (t == 0) atomicMax((int*)ws, __float_as_int(vmx));
    } else if (t < 128) {
        float vmx = colS[t - 64];
        for (int off = 1; off < 64; off <<= 1) vmx = fmaxf(vmx, __shfl_xor(vmx, off));
        if (t == 64) atomicMax(((int*)ws) + 1, __float_as_int(vmx));
    }
}

__global__ __launch_bounds__(TPB) void k_main(const float* __restrict__ q,
                                              const float* __restrict__ k,
                                              const float* __restrict__ v,
                                              const float* __restrict__ ws,
                                              float* __restrict__ out) {
    extern __shared__ f16 smu[];
    float* kv1 = (float*)(smu + NPLANES * 4096);
    float* den = kv1 + 64;
    const int t = threadIdx.x, g = blockIdx.x;
    const int lane = t & 63, wv = t >> 6, wr = wv >> 1, wc = wv & 1;
    const int cl = lane & 31, hh = lane >> 5;
    const float* qg = q + (size_t)g * 16384;
    const float* kg = k + (size_t)g * 16384;
    const float* vg = v + (size_t)g * 16384;
    float* og = out + (size_t)g * 16384;

    // plane map (4096 f16 each)
    f16* QMh = smu +  0 * 4096; f16* QMl = smu +  1 * 4096;  // QM; reused as oT in pinv
    f16* KMh = smu +  2 * 4096; f16* KMl = smu +  3 * 4096;  // KM (persistent)
    f16* P4  = smu +  4 * 4096; f16* P5  = smu +  5 * 4096;  // Kstage -> X -> qstage
    f16* Zrh = smu +  6 * 4096; f16* Zrl = smu +  7 * 4096;  // Z*ZS row-major
    f16* Zth = smu +  8 * 4096; f16* Ztl = smu +  9 * 4096;  // (Z*ZS)^T (B-layout of Z)
    f16* PAh = smu + 10 * 4096; f16* PAl = smu + 11 * 4096;  // Vt -> T1 -> w
    f16* PBh = smu + 12 * 4096; f16* PBl = smu + 13 * 4096;  // S -> T1t -> qk
    f16* KVh = smu + 14 * 4096; f16* KVl = smu + 15 * 4096;  // KV^T (persistent after E)
    f16* T2h = smu + 16 * 4096; f16* T2l = smu + 17 * 4096;  // T2
    f16* oTh = QMh; f16* oTl = QMl;

    // ---- phase 1: pool QM from q ----
    if (t < 64) kv1[t] = 0.f;
    pool_global(qg, QMh, QMl, t);
    __syncthreads();

    // ---- phase E: KV = activ(QM @ K^T) @ [V|1]; also pool KM from staged K ----
    f32x16 kvacc = fzero();
    for (int tt = 0; tt < 4; ++tt) {
        stage_rm(kg + (size_t)tt * 4096, P4, P5, t);
        stage_t (vg + (size_t)tt * 4096, PAh, PAl, t);
        __syncthreads();
        pool_lds(P4, P5, KMh, KMl, t, tt);
        f32x16 sac = mm64q(QMh, QMl, P4, P5, lane, wr, wc, fzero());
#pragma unroll
        for (int m = 0; m < 16; ++m) {
            float x = activ_f(sac[m]);
            FRAG_RC
            split_w(PBh, PBl, R, C, x);
            float vs = x;
            WAVE_SUM32(vs)
            if (cl == 0) atomicAdd(&kv1[R], vs);
        }
        __syncthreads();
        kvacc = mm64q(PBh, PBl, PAh, PAl, lane, wr, wc, kvacc);
        __syncthreads();
    }
    // store KV transposed (B-layout for phase F)
#pragma unroll
    for (int m = 0; m < 16; ++m) {
        FRAG_RC
        split_w(KVh, KVl, C, R, kvacc[m]);
    }

    // ---- phase B: X = activ(QM @ KM^T) ----
    f32x16 xac = mm64q(QMh, QMl, KMh, KMl, lane, wr, wc, fzero());
#pragma unroll
    for (int m = 0; m < 16; ++m) {
        float x = activ_f(xac[m]);
        FRAG_RC
        split_w(P4, P5, R, C, x);
    }
    __syncthreads();

    // ---- phase C: Zs = X^T * scale * ZS (Zr row-major, Zt = B-layout) ----
    {
        const float scale = ZS / (ws[0] * ws[1] + 1e-15f);
        const int r = t >> 2, c0 = (t & 3) << 4;
#pragma unroll
        for (int j = 0; j < 16; ++j) {
            const int c = c0 + j;
            const int o = swi(r, c);
            float xv = join2(P4[o], P5[o]) * scale;
            split_w(Zth, Ztl, r, c, xv);   // Zt[r][c] = Zs^T[c][r]... (B-layout = Zs transposed rm = scale*X)
            split_w(Zrh, Zrl, c, r, xv);   // Zr[c][r] = Zs row-major
        }
    }
    __syncthreads();

    // ---- phase D: 6 Newton-Schulz iterations ----
    for (int it = 0; it < 6; ++it) {
        // T1 = X @ Z  (accumulator carries ZS; descale at split)
        f32x16 a1 = mm64q(P4, P5, Zth, Ztl, lane, wr, wc, fzero());
#pragma unroll
        for (int m = 0; m < 16; ++m) {
            FRAG_RC
            const float t1v = a1[m] * ZINV;
            split_w(PAh, PAl, R, C, t1v);   // T1 rm
            split_w(PBh, PBl, C, R, t1v);   // T1^T rm
        }
        __syncthreads();
        // T2 = T1 @ T1
        f32x16 a2 = mm64q(PAh, PAl, PBh, PBl, lane, wr, wc, fzero());
#pragma unroll
        for (int m = 0; m < 16; ++m) {
            FRAG_RC
            split_w(T2h, T2l, R, C, a2[m]);
        }
        __syncthreads();
        // T4 = T2 @ T1 ; outer = 13I - 15 T1 + 7 T2 - T4, stored transposed
        f32x16 a3 = mm64q(T2h, T2l, PBh, PBl, lane, wr, wc, fzero());
#pragma unroll
        for (int m = 0; m < 16; ++m) {
            FRAG_RC
            const int o = swi(R, C);
            float t1 = join2(PAh[o], PAl[o]);
            float t2 = join2(T2h[o], T2l[o]);
            float ov = ((R == C) ? 13.f : 0.f) - 15.f * t1 + 7.f * t2 - a3[m];
            split_w(oTh, oTl, C, R, ov);
        }
        __syncthreads();
        // Znew*ZS = 0.25 * (Z*ZS) @ outer  (stays scaled)
        f32x16 a4 = mm64q(Zrh, Zrl, oTh, oTl, lane, wr, wc, fzero());
        __syncthreads();  // all reads of Zr/Zt complete before overwrite
#pragma unroll
        for (int m = 0; m < 16; ++m) {
            FRAG_RC
            float x = 0.25f * a4[m];
            split_w(Zrh, Zrl, R, C, x);
            split_w(Zth, Ztl, C, R, x);
        }
        __syncthreads();
    }

    // ---- phase F: out = (activ(q@KM^T) @ Z @ KV) / den ----
    const float kvC = kv1[(wc << 5) + cl];
    for (int tt = 0; tt < 4; ++tt) {
        if (t < 64) den[t] = 0.f;
        stage_rm(qg + (size_t)tt * 4096, P4, P5, t);
        __syncthreads();
        // qk = activ(q @ KM^T)
        f32x16 b1 = mm64q(P4, P5, KMh, KMl, lane, wr, wc, fzero());
#pragma unroll
        for (int m = 0; m < 16; ++m) {
            float x = activ_f(b1[m]);
            FRAG_RC
            split_w(PBh, PBl, R, C, x);
        }
        __syncthreads();
        // w = qk @ Z (accumulator carries ZS); den[R] += sum_C w[R][C]*kv1[C]
        f32x16 b2 = mm64q(PBh, PBl, Zth, Ztl, lane, wr, wc, fzero());
#pragma unroll
        for (int m = 0; m < 16; ++m) {
            FRAG_RC
            const float wv_ = b2[m] * ZINV;
            split_w(PAh, PAl, R, C, wv_);
            float d_ = wv_ * kvC;
            WAVE_SUM32(d_)
            if (cl == 0) atomicAdd(&den[R], d_);
        }
        __syncthreads();
        // prod = w @ KV ; divide ; store
        f32x16 b3 = mm64q(PAh, PAl, KVh, KVl, lane, wr, wc, fzero());
#pragma unroll
        for (int m = 0; m < 16; ++m) {
            FRAG_RC
            const float inv = 1.0f / (den[R] + 1e-12f);
            og[(size_t)((tt << 6) + R) * 64 + C] = b3[m] * inv;
        }
        __syncthreads();
    }
}

extern "C" void kernel_launch(void* const* d_in, const int* in_sizes, int n_in,
                              void* d_out, int out_size, void* d_ws, size_t ws_size,
                              hipStream_t stream) {
    const float* q = (const float*)d_in[0];
    const float* k = (const float*)d_in[1];
    const float* v = (const float*)d_in[2];
    float* out = (float*)d_out;
    float* ws  = (float*)d_ws;
    (void)in_sizes; (void)n_in; (void)out_size; (void)ws_size;

    hipFuncSetAttribute((const void*)k_main,
                        hipFuncAttributeMaxDynamicSharedMemorySize, SMEM_BYTES);

    k_init<<<1, 64, 0, stream>>>(ws);
    k_reduce<<<G_TOT, TPB, 0, stream>>>(q, k, ws);
    k_main<<<G_TOT, TPB, SMEM_BYTES, stream>>>(q, k, v, ws, out);
}

// Round 4
// 931.716 us; speedup vs baseline: 3.0490x; 1.8536x over previous
//
#include <hip/hip_runtime.h>
#include <math.h>

// PnPNystra attention, MFMA v3: 512-thread / 8-wave k_main, 16x16x32 tiles.
// G=4096 groups (B*H), N=256, d=64, L=64.
// All 64x64 matrices in LDS as SPLIT f16: v ~= h + l/2048 (l stored pre-scaled
// by 2048 -> stays in f16 normal range). Every matmul = 3x mfma (hh, h*l, l*h),
// fp32 accumulate. Z (NS iterate) stored scaled by 1024.

#define G_TOT 4096
#define TPB_R 256
#define TPB_M 512
typedef _Float16 f16;
typedef __attribute__((ext_vector_type(2))) _Float16 f16x2;
typedef __attribute__((ext_vector_type(4))) _Float16 f16x4;
typedef __attribute__((ext_vector_type(8))) _Float16 f16x8;
typedef __attribute__((ext_vector_type(4))) float f32x4;
typedef __attribute__((ext_vector_type(16))) float f32x16;

#define NPLANES 18
#define SMEM_BYTES (NPLANES * 4096 * 2 + 2 * 64 * 4)  // 147968 B

#define LSCALE 2048.0f
#define LINV   (1.0f / 2048.0f)
#define ZS     1024.0f
#define ZINV   (1.0f / 1024.0f)

struct HL { f16 h, l; };
__device__ __forceinline__ HL split2(float v) {
    HL r;
    r.h = (f16)v;
    r.l = (f16)((v - (float)r.h) * LSCALE);
    return r;
}
__device__ __forceinline__ float join2(f16 h, f16 l) {
    return (float)h + (float)l * LINV;
}
__device__ __forceinline__ int swi(int r, int c) {
    return (r << 6) + (c ^ ((r & 7) << 3));
}
__device__ __forceinline__ float activ_f(float x) {
    return expf(fminf(x, 5.0f)) + fmaxf(x - 5.0f, 0.0f);
}
__device__ __forceinline__ void split_w(f16* Ph, f16* Pl, int r, int c, float v) {
    HL s = split2(v);
    const int o = swi(r, c);
    Ph[o] = s.h;
    Pl[o] = s.l;
}
__device__ __forceinline__ f16x2 mk2(f16 a, f16 b) { f16x2 r; r[0]=a; r[1]=b; return r; }
__device__ __forceinline__ f16x4 mk4(f16 a, f16 b, f16 c, f16 d) { f16x4 r; r[0]=a;r[1]=b;r[2]=c;r[3]=d; return r; }
__device__ __forceinline__ f32x4 z4() { f32x4 z = {0.f,0.f,0.f,0.f}; return z; }
__device__ __forceinline__ f32x16 z16() {
    f32x16 z;
#pragma unroll
    for (int i = 0; i < 16; ++i) z[i] = 0.f;
    return z;
}

// ---- 16x16 tile matmul (new, k_main): C_tile += A(16 rows at arow..)^T... ----
// A stored [m][k] split planes, B stored [n][k] split planes (B^T row-major).
// arow = A row for this lane (tilebase + (lane&15)), brow likewise for B.
__device__ __forceinline__ f32x4 mm16(const f16* __restrict__ Ah, const f16* __restrict__ Al,
                                      const f16* __restrict__ Bh, const f16* __restrict__ Bl,
                                      int arow, int brow, int kg, f32x4 acc) {
    const int abase = arow << 6, axor = (arow & 7) << 3;
    const int bbase = brow << 6, bxor = (brow & 7) << 3;
    f32x4 ax1 = z4(), ax2 = z4();
#pragma unroll
    for (int s = 0; s < 2; ++s) {
        const int k0 = (s << 5) + (kg << 3);
        const int ao = abase + (k0 ^ axor);
        const int bo = bbase + (k0 ^ bxor);
        f16x8 a_h = *(const f16x8*)(Ah + ao);
        f16x8 a_l = *(const f16x8*)(Al + ao);
        f16x8 b_h = *(const f16x8*)(Bh + bo);
        f16x8 b_l = *(const f16x8*)(Bl + bo);
        acc = __builtin_amdgcn_mfma_f32_16x16x32_f16(a_h, b_h, acc, 0, 0, 0);
        ax1 = __builtin_amdgcn_mfma_f32_16x16x32_f16(a_h, b_l, ax1, 0, 0, 0);
        ax2 = __builtin_amdgcn_mfma_f32_16x16x32_f16(a_l, b_h, ax2, 0, 0, 0);
    }
    acc += (ax1 + ax2) * LINV;
    return acc;
}

// ---- old 32x32-quadrant matmul (kept for k_reduce, unchanged) ----
__device__ __forceinline__ f32x16 mm64q(const f16* __restrict__ Ah, const f16* __restrict__ Al,
                                        const f16* __restrict__ Bh, const f16* __restrict__ Bl,
                                        int lane, int wr, int wc, f32x16 acc) {
    const int cl = lane & 31, hh = lane >> 5;
    const int ar = (wr << 5) + cl, br = (wc << 5) + cl;
    const int abase = ar << 6, axor = (ar & 7) << 3;
    const int bbase = br << 6, bxor = (br & 7) << 3;
    f32x16 ax1 = z16();
    f32x16 ax2 = z16();
#pragma unroll
    for (int ks = 0; ks < 4; ++ks) {
        const int k0 = (ks << 4) + (hh << 3);
        const int ao = abase + (k0 ^ axor);
        const int bo = bbase + (k0 ^ bxor);
        f16x8 a_h = *(const f16x8*)(Ah + ao);
        f16x8 a_l = *(const f16x8*)(Al + ao);
        f16x8 b_h = *(const f16x8*)(Bh + bo);
        f16x8 b_l = *(const f16x8*)(Bl + bo);
        acc = __builtin_amdgcn_mfma_f32_32x32x16_f16(a_h, b_h, acc, 0, 0, 0);
        ax1 = __builtin_amdgcn_mfma_f32_32x32x16_f16(a_h, b_l, ax1, 0, 0, 0);
        ax2 = __builtin_amdgcn_mfma_f32_32x32x16_f16(a_l, b_h, ax2, 0, 0, 0);
    }
    acc += (ax1 + ax2) * LINV;
    return acc;
}

// ---- staging helpers, 512-thread versions (vectorized LDS writes) ----
__device__ __forceinline__ void stage_rm512(const float* __restrict__ src,
                                            f16* Ph, f16* Pl, int t) {
#pragma unroll
    for (int i = 0; i < 2; ++i) {
        const int f = (i << 9) + t;
        const int r = f >> 4, c4 = (f & 15) << 2;
        float4 vv = *(const float4*)(src + (size_t)f * 4);
        const int o = swi(r, c4);
        HL s0 = split2(vv.x), s1 = split2(vv.y), s2 = split2(vv.z), s3 = split2(vv.w);
        *(f16x4*)(Ph + o) = mk4(s0.h, s1.h, s2.h, s3.h);
        *(f16x4*)(Pl + o) = mk4(s0.l, s1.l, s2.l, s3.l);
    }
}

// transposed stage: plane[e][n] = src[n][e]; thread owns a 2(n) x 4(e) block
__device__ __forceinline__ void stage_t512(const float* __restrict__ src,
                                           f16* Ph, f16* Pl, int t) {
    const int n0 = (t >> 4) << 1;
    const int e0 = (t & 15) << 2;
    const float* p = src + (size_t)n0 * 64 + e0;
    float4 v0 = *(const float4*)p;
    float4 v1 = *(const float4*)(p + 64);
    const float* a = (const float*)&v0;
    const float* b = (const float*)&v1;
#pragma unroll
    for (int j = 0; j < 4; ++j) {
        HL sa = split2(a[j]), sb = split2(b[j]);
        const int o = swi(e0 + j, n0);
        *(f16x2*)(Ph + o) = mk2(sa.h, sb.h);
        *(f16x2*)(Pl + o) = mk2(sa.l, sb.l);
    }
}

// pool 2x2-mean landmarks from global fp32 [256][64] -> split planes [64][64]
__device__ __forceinline__ void pool_global512(const float* __restrict__ src,
                                               f16* Ph, f16* Pl, int t) {
    const int L = t >> 3;
    const int d0 = (t & 7) << 3;
    const int tt = L >> 4, ll = L & 15;
    const int rb = ((ll >> 3) << 5) + ((ll & 7) << 1);
    const float* p = src + (size_t)((tt << 6) + rb) * 64 + d0;
    float4 a0 = *(const float4*)p;          float4 a1 = *(const float4*)(p + 4);
    float4 b0 = *(const float4*)(p + 64);   float4 b1 = *(const float4*)(p + 68);
    float4 c0 = *(const float4*)(p + 1024); float4 c1 = *(const float4*)(p + 1028);
    float4 d0_ = *(const float4*)(p + 1088);float4 d1 = *(const float4*)(p + 1092);
    HL s0 = split2(0.25f * (a0.x + b0.x + c0.x + d0_.x));
    HL s1 = split2(0.25f * (a0.y + b0.y + c0.y + d0_.y));
    HL s2 = split2(0.25f * (a0.z + b0.z + c0.z + d0_.z));
    HL s3 = split2(0.25f * (a0.w + b0.w + c0.w + d0_.w));
    HL s4 = split2(0.25f * (a1.x + b1.x + c1.x + d1.x));
    HL s5 = split2(0.25f * (a1.y + b1.y + c1.y + d1.y));
    HL s6 = split2(0.25f * (a1.z + b1.z + c1.z + d1.z));
    HL s7 = split2(0.25f * (a1.w + b1.w + c1.w + d1.w));
    const int o = swi(L, d0);
    *(f16x4*)(Ph + o)     = mk4(s0.h, s1.h, s2.h, s3.h);
    *(f16x4*)(Ph + o + 4) = mk4(s4.h, s5.h, s6.h, s7.h);
    *(f16x4*)(Pl + o)     = mk4(s0.l, s1.l, s2.l, s3.l);
    *(f16x4*)(Pl + o + 4) = mk4(s4.l, s5.l, s6.l, s7.l);
}

// pool landmarks of one staged K tile (tile tt) into KM planes (512 threads)
__device__ __forceinline__ void pool_lds512(const f16* Kh, const f16* Kl,
                                            f16* Ph, f16* Pl, int t, int tt) {
    const int ll = t >> 5, d0 = (t & 31) << 1;
    const int rb = ((ll >> 3) << 5) + ((ll & 7) << 1);
    float s0 = 0.f, s1 = 0.f;
#pragma unroll
    for (int rr = 0; rr < 4; ++rr) {
        const int r = rb + (rr & 1) + ((rr >> 1) << 4);
        const int o = swi(r, d0);
        f16x2 h = *(const f16x2*)(Kh + o);
        f16x2 l = *(const f16x2*)(Kl + o);
        s0 += join2(h[0], l[0]);
        s1 += join2(h[1], l[1]);
    }
    const int L = (tt << 4) + ll;
    HL p0 = split2(0.25f * s0), p1 = split2(0.25f * s1);
    const int o = swi(L, d0);
    *(f16x2*)(Ph + o) = mk2(p0.h, p1.h);
    *(f16x2*)(Pl + o) = mk2(p0.l, p1.l);
}

// ---- old 256-thread pool (kept for k_reduce, unchanged) ----
__device__ __forceinline__ void pool_global_r(const float* __restrict__ src,
                                              f16* Ph, f16* Pl, int t) {
    const int ll = t >> 4, d0 = (t & 15) << 2;
    const int rb = ((ll >> 3) << 5) + ((ll & 7) << 1);
#pragma unroll
    for (int tt = 0; tt < 4; ++tt) {
        const float* p = src + (size_t)((tt << 6) + rb) * 64 + d0;
        float4 a = *(const float4*)p;
        float4 b = *(const float4*)(p + 64);
        float4 c = *(const float4*)(p + 1024);
        float4 d = *(const float4*)(p + 1088);
        const int L = (tt << 4) + ll;
        split_w(Ph, Pl, L, d0 + 0, 0.25f * (a.x + b.x + c.x + d.x));
        split_w(Ph, Pl, L, d0 + 1, 0.25f * (a.y + b.y + c.y + d.y));
        split_w(Ph, Pl, L, d0 + 2, 0.25f * (a.z + b.z + c.z + d.z));
        split_w(Ph, Pl, L, d0 + 3, 0.25f * (a.w + b.w + c.w + d.w));
    }
}

#define WAVE_SUM32(v)            \
    v += __shfl_xor(v, 1);       \
    v += __shfl_xor(v, 2);       \
    v += __shfl_xor(v, 4);       \
    v += __shfl_xor(v, 8);       \
    v += __shfl_xor(v, 16);

__global__ void k_init(float* ws) {
    if (threadIdx.x < 2) ws[threadIdx.x] = 0.0f;
}

// global max of row/col sums of activ(QM @ KM^T) over all groups (unchanged)
__global__ __launch_bounds__(TPB_R) void k_reduce(const float* __restrict__ q,
                                                  const float* __restrict__ k,
                                                  float* __restrict__ ws) {
    __shared__ f16 pls[4 * 4096];
    __shared__ float rowS[64], colS[64];
    const int t = threadIdx.x, g = blockIdx.x;
    const int lane = t & 63, wv = t >> 6, wr = wv >> 1, wc = wv & 1;
    const int cl = lane & 31, hh = lane >> 5;
    if (t < 64) rowS[t] = 0.f;
    else if (t < 128) colS[t - 64] = 0.f;
    pool_global_r(q + (size_t)g * 16384, pls, pls + 4096, t);
    pool_global_r(k + (size_t)g * 16384, pls + 8192, pls + 12288, t);
    __syncthreads();
    f32x16 a = mm64q(pls, pls + 4096, pls + 8192, pls + 12288, lane, wr, wc, z16());
    float colp = 0.f;
#pragma unroll
    for (int m = 0; m < 16; ++m) {
        float x = activ_f(a[m]);
        const int R = (wr << 5) + (m & 3) + ((m >> 2) << 3) + (hh << 2);
        float vs = x;
        WAVE_SUM32(vs)
        if (cl == 0) atomicAdd(&rowS[R], vs);
        colp += x;
    }
    colp += __shfl_xor(colp, 32);
    if (hh == 0) atomicAdd(&colS[(wc << 5) + cl], colp);
    __syncthreads();
    if (t < 64) {
        float vmx = rowS[t];
        for (int off = 1; off < 64; off <<= 1) vmx = fmaxf(vmx, __shfl_xor(vmx, off));
        if (t == 0) atomicMax((int*)ws, __float_as_int(vmx));
    } else if (t < 128) {
        float vmx = colS[t - 64];
        for (int off = 1; off < 64; off <<= 1) vmx = fmaxf(vmx, __shfl_xor(vmx, off));
        if (t == 64) atomicMax(((int*)ws) + 1, __float_as_int(vmx));
    }
}

__global__ __launch_bounds__(TPB_M) void k_main(const float* __restrict__ q,
                                                const float* __restrict__ k,
                                                const float* __restrict__ v,
                                                const float* __restrict__ ws,
                                                float* __restrict__ out) {
    extern __shared__ f16 smu[];
    float* kv1 = (float*)(smu + NPLANES * 4096);
    float* den = kv1 + 64;
    const int t = threadIdx.x, g = blockIdx.x;
    const int lane = t & 63, w = t >> 6;          // 8 waves
    const int ti = w & 3, tj0 = (w >> 2) << 1;    // wave's tile row; first tile col
    const int fr = lane & 15, kg = lane >> 4;     // fragment row/col; k-group
    const int arow = (ti << 4) + fr;
    const int brow0 = (tj0 << 4) + fr;
    const int brow1 = brow0 + 16;
    const int C0 = brow0, C1 = brow1;             // output cols of the two tiles
    const float* Gq = q + (size_t)g * 16384;
    const float* Gk = k + (size_t)g * 16384;
    const float* Gv = v + (size_t)g * 16384;
    float* og = out + (size_t)g * 16384;

    // plane map (4096 f16 each)
    f16* QMh = smu +  0 * 4096; f16* QMl = smu +  1 * 4096;  // QM; reused as oT in pinv
    f16* KMh = smu +  2 * 4096; f16* KMl = smu +  3 * 4096;  // KM (persistent)
    f16* P4  = smu +  4 * 4096; f16* P5  = smu +  5 * 4096;  // Kstage -> X -> qstage
    f16* Zrh = smu +  6 * 4096; f16* Zrl = smu +  7 * 4096;  // Z*ZS row-major
    f16* Zth = smu +  8 * 4096; f16* Ztl = smu +  9 * 4096;  // (Z*ZS)^T (B-layout)
    f16* PAh = smu + 10 * 4096; f16* PAl = smu + 11 * 4096;  // Vt -> T1 -> w
    f16* PBh = smu + 12 * 4096; f16* PBl = smu + 13 * 4096;  // S -> T1t -> qk
    f16* KVh = smu + 14 * 4096; f16* KVl = smu + 15 * 4096;  // KV^T (persistent)
    f16* T2h = smu + 16 * 4096; f16* T2l = smu + 17 * 4096;  // T2
    f16* oTh = QMh; f16* oTl = QMl;

    // ---- phase 1: pool QM from q ----
    if (t < 64) kv1[t] = 0.f;
    pool_global512(Gq, QMh, QMl, t);
    __syncthreads();

    // ---- phase E: KV = activ(QM @ K^T) @ [V|1]; pool KM from staged K ----
    f32x4 kva0 = z4(), kva1 = z4();
    for (int tt = 0; tt < 4; ++tt) {
        stage_rm512(Gk + (size_t)tt * 4096, P4, P5, t);
        stage_t512 (Gv + (size_t)tt * 4096, PAh, PAl, t);
        __syncthreads();
        pool_lds512(P4, P5, KMh, KMl, t, tt);
        f32x4 s0 = mm16(QMh, QMl, P4, P5, arow, brow0, kg, z4());
        f32x4 s1 = mm16(QMh, QMl, P4, P5, arow, brow1, kg, z4());
#pragma unroll
        for (int m = 0; m < 4; ++m) {
            const int R = (ti << 4) + (kg << 2) + m;
            const float x0 = activ_f(s0[m]);
            const float x1 = activ_f(s1[m]);
            split_w(PBh, PBl, R, C0, x0);
            split_w(PBh, PBl, R, C1, x1);
            float vs = x0 + x1;
            vs += __shfl_xor(vs, 1); vs += __shfl_xor(vs, 2);
            vs += __shfl_xor(vs, 4); vs += __shfl_xor(vs, 8);
            if (fr == 0) atomicAdd(&kv1[R], vs);
        }
        __syncthreads();
        kva0 = mm16(PBh, PBl, PAh, PAl, arow, brow0, kg, kva0);
        kva1 = mm16(PBh, PBl, PAh, PAl, arow, brow1, kg, kva1);
        __syncthreads();
    }
    // store KV transposed (B-layout for phase F)
#pragma unroll
    for (int m = 0; m < 4; ++m) {
        const int R = (ti << 4) + (kg << 2) + m;
        split_w(KVh, KVl, C0, R, kva0[m]);
        split_w(KVh, KVl, C1, R, kva1[m]);
    }

    // ---- phase B: X = activ(QM @ KM^T) -> P4/P5 ----
    {
        f32x4 x0 = mm16(QMh, QMl, KMh, KMl, arow, brow0, kg, z4());
        f32x4 x1 = mm16(QMh, QMl, KMh, KMl, arow, brow1, kg, z4());
#pragma unroll
        for (int m = 0; m < 4; ++m) {
            const int R = (ti << 4) + (kg << 2) + m;
            split_w(P4, P5, R, C0, activ_f(x0[m]));
            split_w(P4, P5, R, C1, activ_f(x1[m]));
        }
    }
    __syncthreads();

    // ---- phase C: Zs = X^T * scale * ZS (Zr row-major, Zt B-layout) ----
    {
        const float scale = ZS / (ws[0] * ws[1] + 1e-15f);
#pragma unroll
        for (int i = 0; i < 2; ++i) {
            const int bi = (i << 9) + t;
            const int r0 = (bi >> 5) << 1, c0 = (bi & 31) << 1;
            const int o00 = swi(r0, c0), o10 = swi(r0 + 1, c0);
            const float v00 = join2(P4[o00], P5[o00]) * scale;
            const float v01 = join2(P4[o00 + 1], P5[o00 + 1]) * scale;
            const float v10 = join2(P4[o10], P5[o10]) * scale;
            const float v11 = join2(P4[o10 + 1], P5[o10 + 1]) * scale;
            HL s00 = split2(v00), s01 = split2(v01), s10 = split2(v10), s11 = split2(v11);
            // Zt[r][c] = scale*X[r][c]
            *(f16x2*)(Zth + o00) = mk2(s00.h, s01.h);
            *(f16x2*)(Ztl + o00) = mk2(s00.l, s01.l);
            *(f16x2*)(Zth + o10) = mk2(s10.h, s11.h);
            *(f16x2*)(Ztl + o10) = mk2(s10.l, s11.l);
            // Zr[c][r] = scale*X[r][c]
            const int p0 = swi(c0, r0), p1 = swi(c0 + 1, r0);
            *(f16x2*)(Zrh + p0) = mk2(s00.h, s10.h);
            *(f16x2*)(Zrl + p0) = mk2(s00.l, s10.l);
            *(f16x2*)(Zrh + p1) = mk2(s01.h, s11.h);
            *(f16x2*)(Zrl + p1) = mk2(s01.l, s11.l);
        }
    }
    __syncthreads();

    // ---- phase D: 6 Newton-Schulz iterations ----
    for (int it = 0; it < 6; ++it) {
        // T1 = X @ Z (acc carries ZS)
        f32x4 a0 = mm16(P4, P5, Zth, Ztl, arow, brow0, kg, z4());
        f32x4 a1 = mm16(P4, P5, Zth, Ztl, arow, brow1, kg, z4());
#pragma unroll
        for (int m = 0; m < 4; ++m) {
            const int R = (ti << 4) + (kg << 2) + m;
            const float t10 = a0[m] * ZINV, t11 = a1[m] * ZINV;
            split_w(PAh, PAl, R, C0, t10);   // T1 rm
            split_w(PAh, PAl, R, C1, t11);
            split_w(PBh, PBl, C0, R, t10);   // T1^T rm
            split_w(PBh, PBl, C1, R, t11);
        }
        __syncthreads();
        // T2 = T1 @ T1
        f32x4 b0 = mm16(PAh, PAl, PBh, PBl, arow, brow0, kg, z4());
        f32x4 b1 = mm16(PAh, PAl, PBh, PBl, arow, brow1, kg, z4());
#pragma unroll
        for (int m = 0; m < 4; ++m) {
            const int R = (ti << 4) + (kg << 2) + m;
            split_w(T2h, T2l, R, C0, b0[m]);
            split_w(T2h, T2l, R, C1, b1[m]);
        }
        __syncthreads();
        // T4 = T2 @ T1 ; outer = 13I - 15 T1 + 7 T2 - T4, stored transposed
        f32x4 c0a = mm16(T2h, T2l, PBh, PBl, arow, brow0, kg, z4());
        f32x4 c1a = mm16(T2h, T2l, PBh, PBl, arow, brow1, kg, z4());
#pragma unroll
        for (int m = 0; m < 4; ++m) {
            const int R = (ti << 4) + (kg << 2) + m;
#pragma unroll
            for (int tile = 0; tile < 2; ++tile) {
                const int C = tile ? C1 : C0;
                const int o = swi(R, C);
                const float t1 = join2(PAh[o], PAl[o]);
                const float t2 = join2(T2h[o], T2l[o]);
                const float t4 = tile ? c1a[m] : c0a[m];
                const float ov = ((R == C) ? 13.f : 0.f) - 15.f * t1 + 7.f * t2 - t4;
                split_w(oTh, oTl, C, R, ov);
            }
        }
        __syncthreads();
        // Znew*ZS = 0.25 * (Z*ZS) @ outer
        f32x4 d0 = mm16(Zrh, Zrl, oTh, oTl, arow, brow0, kg, z4());
        f32x4 d1 = mm16(Zrh, Zrl, oTh, oTl, arow, brow1, kg, z4());
        __syncthreads();  // all reads of Zr/Zt complete before overwrite
#pragma unroll
        for (int m = 0; m < 4; ++m) {
            const int R = (ti << 4) + (kg << 2) + m;
            const float z0 = 0.25f * d0[m], z1 = 0.25f * d1[m];
            split_w(Zrh, Zrl, R, C0, z0);
            split_w(Zrh, Zrl, R, C1, z1);
            split_w(Zth, Ztl, C0, R, z0);
            split_w(Zth, Ztl, C1, R, z1);
        }
        __syncthreads();
    }

    // ---- phase F: out = (activ(q@KM^T) @ Z @ KV) / den ----
    const float kvC0 = kv1[C0];
    const float kvC1 = kv1[C1];
    for (int tt = 0; tt < 4; ++tt) {
        if (t < 64) den[t] = 0.f;
        stage_rm512(Gq + (size_t)tt * 4096, P4, P5, t);
        __syncthreads();
        // qk = activ(q @ KM^T)
        f32x4 q0 = mm16(P4, P5, KMh, KMl, arow, brow0, kg, z4());
        f32x4 q1 = mm16(P4, P5, KMh, KMl, arow, brow1, kg, z4());
#pragma unroll
        for (int m = 0; m < 4; ++m) {
            const int R = (ti << 4) + (kg << 2) + m;
            split_w(PBh, PBl, R, C0, activ_f(q0[m]));
            split_w(PBh, PBl, R, C1, activ_f(q1[m]));
        }
        __syncthreads();
        // w = qk @ Z (acc carries ZS); den[R] += sum_C w[R][C]*kv1[C]
        f32x4 w0 = mm16(PBh, PBl, Zth, Ztl, arow, brow0, kg, z4());
        f32x4 w1 = mm16(PBh, PBl, Zth, Ztl, arow, brow1, kg, z4());
#pragma unroll
        for (int m = 0; m < 4; ++m) {
            const int R = (ti << 4) + (kg << 2) + m;
            const float wv0 = w0[m] * ZINV, wv1 = w1[m] * ZINV;
            split_w(PAh, PAl, R, C0, wv0);
            split_w(PAh, PAl, R, C1, wv1);
            float d_ = wv0 * kvC0 + wv1 * kvC1;
            d_ += __shfl_xor(d_, 1); d_ += __shfl_xor(d_, 2);
            d_ += __shfl_xor(d_, 4); d_ += __shfl_xor(d_, 8);
            if (fr == 0) atomicAdd(&den[R], d_);
        }
        __syncthreads();
        // prod = w @ KV ; divide ; store
        f32x4 p0 = mm16(PAh, PAl, KVh, KVl, arow, brow0, kg, z4());
        f32x4 p1 = mm16(PAh, PAl, KVh, KVl, arow, brow1, kg, z4());
#pragma unroll
        for (int m = 0; m < 4; ++m) {
            const int R = (ti << 4) + (kg << 2) + m;
            const float inv = 1.0f / (den[R] + 1e-12f);
            og[(size_t)((tt << 6) + R) * 64 + C0] = p0[m] * inv;
            og[(size_t)((tt << 6) + R) * 64 + C1] = p1[m] * inv;
        }
        __syncthreads();
    }
}

extern "C" void kernel_launch(void* const* d_in, const int* in_sizes, int n_in,
                              void* d_out, int out_size, void* d_ws, size_t ws_size,
                              hipStream_t stream) {
    const float* q = (const float*)d_in[0];
    const float* k = (const float*)d_in[1];
    const float* v = (const float*)d_in[2];
    float* out = (float*)d_out;
    float* ws  = (float*)d_ws;
    (void)in_sizes; (void)n_in; (void)out_size; (void)ws_size;

    hipFuncSetAttribute((const void*)k_main,
                        hipFuncAttributeMaxDynamicSharedMemorySize, SMEM_BYTES);

    k_init<<<1, 64, 0, stream>>>(ws);
    k_reduce<<<G_TOT, TPB_R, 0, stream>>>(q, k, ws);
    k_main<<<G_TOT, TPB_M, SMEM_BYTES, stream>>>(q, k, v, ws, out);
}

// Round 6
// 908.981 us; speedup vs baseline: 3.1252x; 1.0250x over previous
//
#include <hip/hip_runtime.h>
#include <math.h>

// PnPNystra attention, MFMA v4: 1024-thread / 16-wave k_main (4 waves/SIMD),
// one 16x16 tile per wave per 64x64 matmul, register-prefetch staging.
// G=4096 groups (B*H), N=256, d=64, L=64.
// All 64x64 matrices in LDS as SPLIT f16: v ~= h + l/2048 (l stored pre-scaled
// by 2048 -> stays in f16 normal range). Every matmul = 3x mfma (hh, h*l, l*h),
// fp32 accumulate. Z (NS iterate) stored scaled by 1024.
// (Resubmission of round-5 kernel: bench failed on infra, no signal.)

#define G_TOT 4096
#define TPB_R 256
#define TPB_M 1024
typedef _Float16 f16;
typedef __attribute__((ext_vector_type(2))) _Float16 f16x2;
typedef __attribute__((ext_vector_type(4))) _Float16 f16x4;
typedef __attribute__((ext_vector_type(8))) _Float16 f16x8;
typedef __attribute__((ext_vector_type(4))) float f32x4;
typedef __attribute__((ext_vector_type(16))) float f32x16;

#define NPLANES 18
#define SMEM_BYTES (NPLANES * 4096 * 2 + 2 * 64 * 4)  // 147968 B

#define LSCALE 2048.0f
#define LINV   (1.0f / 2048.0f)
#define ZS     1024.0f
#define ZINV   (1.0f / 1024.0f)

struct HL { f16 h, l; };
__device__ __forceinline__ HL split2(float v) {
    HL r;
    r.h = (f16)v;
    r.l = (f16)((v - (float)r.h) * LSCALE);
    return r;
}
__device__ __forceinline__ float join2(f16 h, f16 l) {
    return (float)h + (float)l * LINV;
}
__device__ __forceinline__ int swi(int r, int c) {
    return (r << 6) + (c ^ ((r & 7) << 3));
}
__device__ __forceinline__ float activ_f(float x) {
    return expf(fminf(x, 5.0f)) + fmaxf(x - 5.0f, 0.0f);
}
__device__ __forceinline__ void split_w(f16* Ph, f16* Pl, int r, int c, float v) {
    HL s = split2(v);
    const int o = swi(r, c);
    Ph[o] = s.h;
    Pl[o] = s.l;
}
__device__ __forceinline__ f16x2 mk2(f16 a, f16 b) { f16x2 r; r[0]=a; r[1]=b; return r; }
__device__ __forceinline__ f16x4 mk4(f16 a, f16 b, f16 c, f16 d) { f16x4 r; r[0]=a;r[1]=b;r[2]=c;r[3]=d; return r; }
__device__ __forceinline__ f32x4 z4() { f32x4 z = {0.f,0.f,0.f,0.f}; return z; }
__device__ __forceinline__ f32x16 z16() {
    f32x16 z;
#pragma unroll
    for (int i = 0; i < 16; ++i) z[i] = 0.f;
    return z;
}

// ---- 16x16 tile matmul: one wave computes C[arow-tile][brow-tile] ----
// A stored [m][k] split planes, B stored [n][k] split planes (B^T row-major).
__device__ __forceinline__ f32x4 mm16(const f16* __restrict__ Ah, const f16* __restrict__ Al,
                                      const f16* __restrict__ Bh, const f16* __restrict__ Bl,
                                      int arow, int brow, int kg, f32x4 acc) {
    const int abase = arow << 6, axor = (arow & 7) << 3;
    const int bbase = brow << 6, bxor = (brow & 7) << 3;
    f32x4 ax1 = z4(), ax2 = z4();
#pragma unroll
    for (int s = 0; s < 2; ++s) {
        const int k0 = (s << 5) + (kg << 3);
        const int ao = abase + (k0 ^ axor);
        const int bo = bbase + (k0 ^ bxor);
        f16x8 a_h = *(const f16x8*)(Ah + ao);
        f16x8 a_l = *(const f16x8*)(Al + ao);
        f16x8 b_h = *(const f16x8*)(Bh + bo);
        f16x8 b_l = *(const f16x8*)(Bl + bo);
        acc = __builtin_amdgcn_mfma_f32_16x16x32_f16(a_h, b_h, acc, 0, 0, 0);
        ax1 = __builtin_amdgcn_mfma_f32_16x16x32_f16(a_h, b_l, ax1, 0, 0, 0);
        ax2 = __builtin_amdgcn_mfma_f32_16x16x32_f16(a_l, b_h, ax2, 0, 0, 0);
    }
    acc += (ax1 + ax2) * LINV;
    return acc;
}

// ---- old 32x32-quadrant matmul (kept for k_reduce, unchanged) ----
__device__ __forceinline__ f32x16 mm64q(const f16* __restrict__ Ah, const f16* __restrict__ Al,
                                        const f16* __restrict__ Bh, const f16* __restrict__ Bl,
                                        int lane, int wr, int wc, f32x16 acc) {
    const int cl = lane & 31, hh = lane >> 5;
    const int ar = (wr << 5) + cl, br = (wc << 5) + cl;
    const int abase = ar << 6, axor = (ar & 7) << 3;
    const int bbase = br << 6, bxor = (br & 7) << 3;
    f32x16 ax1 = z16();
    f32x16 ax2 = z16();
#pragma unroll
    for (int ks = 0; ks < 4; ++ks) {
        const int k0 = (ks << 4) + (hh << 3);
        const int ao = abase + (k0 ^ axor);
        const int bo = bbase + (k0 ^ bxor);
        f16x8 a_h = *(const f16x8*)(Ah + ao);
        f16x8 a_l = *(const f16x8*)(Al + ao);
        f16x8 b_h = *(const f16x8*)(Bh + bo);
        f16x8 b_l = *(const f16x8*)(Bl + bo);
        acc = __builtin_amdgcn_mfma_f32_32x32x16_f16(a_h, b_h, acc, 0, 0, 0);
        ax1 = __builtin_amdgcn_mfma_f32_32x32x16_f16(a_h, b_l, ax1, 0, 0, 0);
        ax2 = __builtin_amdgcn_mfma_f32_32x32x16_f16(a_l, b_h, ax2, 0, 0, 0);
    }
    acc += (ax1 + ax2) * LINV;
    return acc;
}

// ---- staging: 1024-thread register-prefetch helpers ----
// row-major 64x64 tile: thread t owns float4 #t
__device__ __forceinline__ void wr_rm(float4 vv, f16* Ph, f16* Pl, int t) {
    const int r = t >> 4, c4 = (t & 15) << 2;
    const int o = swi(r, c4);
    HL s0 = split2(vv.x), s1 = split2(vv.y), s2 = split2(vv.z), s3 = split2(vv.w);
    *(f16x4*)(Ph + o) = mk4(s0.h, s1.h, s2.h, s3.h);
    *(f16x4*)(Pl + o) = mk4(s0.l, s1.l, s2.l, s3.l);
}
// transposed V stage: thread t owns rows n0=2*(t>>5), n0+1 at cols e0=(t&31)*2, e0+1
__device__ __forceinline__ void ld_vt(const float* __restrict__ src, int t,
                                      float2& va, float2& vb) {
    const int n0 = (t >> 5) << 1, e0 = (t & 31) << 1;
    va = *(const float2*)(src + (size_t)n0 * 64 + e0);
    vb = *(const float2*)(src + (size_t)(n0 + 1) * 64 + e0);
}
__device__ __forceinline__ void wr_vt(float2 va, float2 vb, f16* Ph, f16* Pl, int t) {
    const int n0 = (t >> 5) << 1, e0 = (t & 31) << 1;
    HL ax = split2(va.x), ay = split2(va.y), bx = split2(vb.x), by = split2(vb.y);
    const int o0 = swi(e0, n0), o1 = swi(e0 + 1, n0);
    *(f16x2*)(Ph + o0) = mk2(ax.h, bx.h);
    *(f16x2*)(Pl + o0) = mk2(ax.l, bx.l);
    *(f16x2*)(Ph + o1) = mk2(ay.h, by.h);
    *(f16x2*)(Pl + o1) = mk2(ay.l, by.l);
}

// pool 2x2-mean landmarks from global fp32 [256][64] -> split planes [64][64]
// 1024 threads: one landmark x 4 d's per thread
__device__ __forceinline__ void pool_global1024(const float* __restrict__ src,
                                                f16* Ph, f16* Pl, int t) {
    const int L = t >> 4, d0 = (t & 15) << 2;
    const int nb = ((L >> 3) << 5) + ((L & 7) << 1);
    const float* p = src + (size_t)nb * 64 + d0;
    float4 a = *(const float4*)p;
    float4 b = *(const float4*)(p + 64);
    float4 c = *(const float4*)(p + 1024);
    float4 d = *(const float4*)(p + 1088);
    HL s0 = split2(0.25f * (a.x + b.x + c.x + d.x));
    HL s1 = split2(0.25f * (a.y + b.y + c.y + d.y));
    HL s2 = split2(0.25f * (a.z + b.z + c.z + d.z));
    HL s3 = split2(0.25f * (a.w + b.w + c.w + d.w));
    const int o = swi(L, d0);
    *(f16x4*)(Ph + o) = mk4(s0.h, s1.h, s2.h, s3.h);
    *(f16x4*)(Pl + o) = mk4(s0.l, s1.l, s2.l, s3.l);
}

// pool landmarks of one staged K tile (tile tt) into KM planes (first 512 threads)
__device__ __forceinline__ void pool_lds512(const f16* Kh, const f16* Kl,
                                            f16* Ph, f16* Pl, int t, int tt) {
    const int ll = t >> 5, d0 = (t & 31) << 1;
    const int rb = ((ll >> 3) << 5) + ((ll & 7) << 1);
    float s0 = 0.f, s1 = 0.f;
#pragma unroll
    for (int rr = 0; rr < 4; ++rr) {
        const int r = rb + (rr & 1) + ((rr >> 1) << 4);
        const int o = swi(r, d0);
        f16x2 h = *(const f16x2*)(Kh + o);
        f16x2 l = *(const f16x2*)(Kl + o);
        s0 += join2(h[0], l[0]);
        s1 += join2(h[1], l[1]);
    }
    const int L = (tt << 4) + ll;
    HL p0 = split2(0.25f * s0), p1 = split2(0.25f * s1);
    const int o = swi(L, d0);
    *(f16x2*)(Ph + o) = mk2(p0.h, p1.h);
    *(f16x2*)(Pl + o) = mk2(p0.l, p1.l);
}

// ---- old 256-thread pool (kept for k_reduce, unchanged) ----
__device__ __forceinline__ void pool_global_r(const float* __restrict__ src,
                                              f16* Ph, f16* Pl, int t) {
    const int ll = t >> 4, d0 = (t & 15) << 2;
    const int rb = ((ll >> 3) << 5) + ((ll & 7) << 1);
#pragma unroll
    for (int tt = 0; tt < 4; ++tt) {
        const float* p = src + (size_t)((tt << 6) + rb) * 64 + d0;
        float4 a = *(const float4*)p;
        float4 b = *(const float4*)(p + 64);
        float4 c = *(const float4*)(p + 1024);
        float4 d = *(const float4*)(p + 1088);
        const int L = (tt << 4) + ll;
        split_w(Ph, Pl, L, d0 + 0, 0.25f * (a.x + b.x + c.x + d.x));
        split_w(Ph, Pl, L, d0 + 1, 0.25f * (a.y + b.y + c.y + d.y));
        split_w(Ph, Pl, L, d0 + 2, 0.25f * (a.z + b.z + c.z + d.z));
        split_w(Ph, Pl, L, d0 + 3, 0.25f * (a.w + b.w + c.w + d.w));
    }
}

#define WAVE_SUM32(v)            \
    v += __shfl_xor(v, 1);       \
    v += __shfl_xor(v, 2);       \
    v += __shfl_xor(v, 4);       \
    v += __shfl_xor(v, 8);       \
    v += __shfl_xor(v, 16);

__global__ void k_init(float* ws) {
    if (threadIdx.x < 2) ws[threadIdx.x] = 0.0f;
}

// global max of row/col sums of activ(QM @ KM^T) over all groups (unchanged)
__global__ __launch_bounds__(TPB_R) void k_reduce(const float* __restrict__ q,
                                                  const float* __restrict__ k,
                                                  float* __restrict__ ws) {
    __shared__ f16 pls[4 * 4096];
    __shared__ float rowS[64], colS[64];
    const int t = threadIdx.x, g = blockIdx.x;
    const int lane = t & 63, wv = t >> 6, wr = wv >> 1, wc = wv & 1;
    const int cl = lane & 31, hh = lane >> 5;
    if (t < 64) rowS[t] = 0.f;
    else if (t < 128) colS[t - 64] = 0.f;
    pool_global_r(q + (size_t)g * 16384, pls, pls + 4096, t);
    pool_global_r(k + (size_t)g * 16384, pls + 8192, pls + 12288, t);
    __syncthreads();
    f32x16 a = mm64q(pls, pls + 4096, pls + 8192, pls + 12288, lane, wr, wc, z16());
    float colp = 0.f;
#pragma unroll
    for (int m = 0; m < 16; ++m) {
        float x = activ_f(a[m]);
        const int R = (wr << 5) + (m & 3) + ((m >> 2) << 3) + (hh << 2);
        float vs = x;
        WAVE_SUM32(vs)
        if (cl == 0) atomicAdd(&rowS[R], vs);
        colp += x;
    }
    colp += __shfl_xor(colp, 32);
    if (hh == 0) atomicAdd(&colS[(wc << 5) + cl], colp);
    __syncthreads();
    if (t < 64) {
        float vmx = rowS[t];
        for (int off = 1; off < 64; off <<= 1) vmx = fmaxf(vmx, __shfl_xor(vmx, off));
        if (t == 0) atomicMax((int*)ws, __float_as_int(vmx));
    } else if (t < 128) {
        float vmx = colS[t - 64];
        for (int off = 1; off < 64; off <<= 1) vmx = fmaxf(vmx, __shfl_xor(vmx, off));
        if (t == 64) atomicMax(((int*)ws) + 1, __float_as_int(vmx));
    }
}

__global__ __launch_bounds__(TPB_M, 4) void k_main(const float* __restrict__ q,
                                                   const float* __restrict__ k,
                                                   const float* __restrict__ v,
                                                   const float* __restrict__ ws,
                                                   float* __restrict__ out) {
    extern __shared__ f16 smu[];
    float* kv1 = (float*)(smu + NPLANES * 4096);
    float* den = kv1 + 64;
    const int t = threadIdx.x, g = blockIdx.x;
    const int lane = t & 63, w = t >> 6;          // 16 waves
    const int ti = w & 3, tj = w >> 2;            // wave's tile (row, col)
    const int fr = lane & 15, kg = lane >> 4;
    const int arow = (ti << 4) + fr;
    const int brow = (tj << 4) + fr;
    const int C = brow;                            // output col
    const int Rb = (ti << 4) + (kg << 2);          // output row base (+m)
    const float* Gq = q + (size_t)g * 16384;
    const float* Gk = k + (size_t)g * 16384;
    const float* Gv = v + (size_t)g * 16384;
    float* og = out + (size_t)g * 16384;

    // plane map (4096 f16 each)
    f16* QMh = smu +  0 * 4096; f16* QMl = smu +  1 * 4096;  // QM; reused as oT in pinv
    f16* KMh = smu +  2 * 4096; f16* KMl = smu +  3 * 4096;  // KM (persistent)
    f16* P4  = smu +  4 * 4096; f16* P5  = smu +  5 * 4096;  // Kstage -> X -> qstage
    f16* Zrh = smu +  6 * 4096; f16* Zrl = smu +  7 * 4096;  // Z*ZS row-major
    f16* Zth = smu +  8 * 4096; f16* Ztl = smu +  9 * 4096;  // (Z*ZS)^T (B-layout)
    f16* PAh = smu + 10 * 4096; f16* PAl = smu + 11 * 4096;  // Vt -> T1 -> w
    f16* PBh = smu + 12 * 4096; f16* PBl = smu + 13 * 4096;  // S -> T1t -> qk
    f16* KVh = smu + 14 * 4096; f16* KVl = smu + 15 * 4096;  // KV^T (persistent)
    f16* T2h = smu + 16 * 4096; f16* T2l = smu + 17 * 4096;  // T2
    f16* oTh = QMh; f16* oTl = QMl;

    // ---- phase A: pool QM from q ----
    if (t < 64) kv1[t] = 0.f;
    pool_global1024(Gq, QMh, QMl, t);
    __syncthreads();

    // ---- phase E: KV = activ(QM @ K^T) @ [V|1]; pool KM from staged K ----
    f32x4 kva = z4();
    float4 kreg = *(const float4*)(Gk + (size_t)t * 4);
    float2 va, vb;
    ld_vt(Gv, t, va, vb);
    for (int tt = 0; tt < 4; ++tt) {
        wr_rm(kreg, P4, P5, t);
        wr_vt(va, vb, PAh, PAl, t);
        if (tt < 3) {   // prefetch next tile while this one is consumed
            kreg = *(const float4*)(Gk + (size_t)(tt + 1) * 4096 + (size_t)t * 4);
            ld_vt(Gv + (size_t)(tt + 1) * 4096, t, va, vb);
        }
        __syncthreads();
        if (t < 512) pool_lds512(P4, P5, KMh, KMl, t, tt);
        f32x4 s = mm16(QMh, QMl, P4, P5, arow, brow, kg, z4());
#pragma unroll
        for (int m = 0; m < 4; ++m) {
            const int R = Rb + m;
            const float x = activ_f(s[m]);
            split_w(PBh, PBl, R, C, x);
            float vs = x;
            vs += __shfl_xor(vs, 1); vs += __shfl_xor(vs, 2);
            vs += __shfl_xor(vs, 4); vs += __shfl_xor(vs, 8);
            if (fr == 0) atomicAdd(&kv1[R], vs);
        }
        __syncthreads();
        kva = mm16(PBh, PBl, PAh, PAl, arow, brow, kg, kva);
        __syncthreads();
    }
    // store KV transposed (B-layout for phase F)
#pragma unroll
    for (int m = 0; m < 4; ++m) split_w(KVh, KVl, C, Rb + m, kva[m]);

    // ---- phase B: X = activ(QM @ KM^T) -> P4/P5 ----
    {
        f32x4 x0 = mm16(QMh, QMl, KMh, KMl, arow, brow, kg, z4());
#pragma unroll
        for (int m = 0; m < 4; ++m) split_w(P4, P5, Rb + m, C, activ_f(x0[m]));
    }
    __syncthreads();

    // ---- phase C: Zs = X^T * scale * ZS (Zr row-major, Zt B-layout) ----
    {
        const float scale = ZS / (ws[0] * ws[1] + 1e-15f);
        const int r0 = (t >> 5) << 1, c0 = (t & 31) << 1;
        const int o00 = swi(r0, c0), o10 = swi(r0 + 1, c0);
        const float v00 = join2(P4[o00], P5[o00]) * scale;
        const float v01 = join2(P4[o00 + 1], P5[o00 + 1]) * scale;
        const float v10 = join2(P4[o10], P5[o10]) * scale;
        const float v11 = join2(P4[o10 + 1], P5[o10 + 1]) * scale;
        HL s00 = split2(v00), s01 = split2(v01), s10 = split2(v10), s11 = split2(v11);
        *(f16x2*)(Zth + o00) = mk2(s00.h, s01.h);
        *(f16x2*)(Ztl + o00) = mk2(s00.l, s01.l);
        *(f16x2*)(Zth + o10) = mk2(s10.h, s11.h);
        *(f16x2*)(Ztl + o10) = mk2(s10.l, s11.l);
        const int p0 = swi(c0, r0), p1 = swi(c0 + 1, r0);
        *(f16x2*)(Zrh + p0) = mk2(s00.h, s10.h);
        *(f16x2*)(Zrl + p0) = mk2(s00.l, s10.l);
        *(f16x2*)(Zrh + p1) = mk2(s01.h, s11.h);
        *(f16x2*)(Zrl + p1) = mk2(s01.l, s11.l);
    }
    __syncthreads();

    // ---- phase D: 6 Newton-Schulz iterations ----
    for (int it = 0; it < 6; ++it) {
        // T1 = X @ Z (acc carries ZS)
        f32x4 a0 = mm16(P4, P5, Zth, Ztl, arow, brow, kg, z4());
#pragma unroll
        for (int m = 0; m < 4; ++m) {
            const int R = Rb + m;
            const float t1 = a0[m] * ZINV;
            split_w(PAh, PAl, R, C, t1);   // T1 rm
            split_w(PBh, PBl, C, R, t1);   // T1^T rm
        }
        __syncthreads();
        // T2 = T1 @ T1
        f32x4 b0 = mm16(PAh, PAl, PBh, PBl, arow, brow, kg, z4());
#pragma unroll
        for (int m = 0; m < 4; ++m) split_w(T2h, T2l, Rb + m, C, b0[m]);
        __syncthreads();
        // T4 = T2 @ T1 ; outer = 13I - 15 T1 + 7 T2 - T4, stored transposed
        f32x4 c0a = mm16(T2h, T2l, PBh, PBl, arow, brow, kg, z4());
#pragma unroll
        for (int m = 0; m < 4; ++m) {
            const int R = Rb + m;
            const int o = swi(R, C);
            const float t1 = join2(PAh[o], PAl[o]);
            const float t2 = join2(T2h[o], T2l[o]);
            const float ov = ((R == C) ? 13.f : 0.f) - 15.f * t1 + 7.f * t2 - c0a[m];
            split_w(oTh, oTl, C, R, ov);
        }
        __syncthreads();
        // Znew*ZS = 0.25 * (Z*ZS) @ outer
        f32x4 d0 = mm16(Zrh, Zrl, oTh, oTl, arow, brow, kg, z4());
        __syncthreads();  // all reads of Zr/Zt complete before overwrite
#pragma unroll
        for (int m = 0; m < 4; ++m) {
            const int R = Rb + m;
            const float z0 = 0.25f * d0[m];
            split_w(Zrh, Zrl, R, C, z0);
            split_w(Zth, Ztl, C, R, z0);
        }
        __syncthreads();
    }

    // ---- phase F: out = (activ(q@KM^T) @ Z @ KV) / den ----
    const float kvC = kv1[C];
    float4 qreg = *(const float4*)(Gq + (size_t)t * 4);
    for (int tt = 0; tt < 4; ++tt) {
        if (t < 64) den[t] = 0.f;
        wr_rm(qreg, P4, P5, t);
        if (tt < 3) qreg = *(const float4*)(Gq + (size_t)(tt + 1) * 4096 + (size_t)t * 4);
        __syncthreads();
        // qk = activ(q @ KM^T)
        f32x4 q0 = mm16(P4, P5, KMh, KMl, arow, brow, kg, z4());
#pragma unroll
        for (int m = 0; m < 4; ++m) split_w(PBh, PBl, Rb + m, C, activ_f(q0[m]));
        __syncthreads();
        // w = qk @ Z (acc carries ZS); den[R] += sum_C w[R][C]*kv1[C]
        f32x4 w0 = mm16(PBh, PBl, Zth, Ztl, arow, brow, kg, z4());
#pragma unroll
        for (int m = 0; m < 4; ++m) {
            const int R = Rb + m;
            const float wv = w0[m] * ZINV;
            split_w(PAh, PAl, R, C, wv);
            float d_ = wv * kvC;
            d_ += __shfl_xor(d_, 1); d_ += __shfl_xor(d_, 2);
            d_ += __shfl_xor(d_, 4); d_ += __shfl_xor(d_, 8);
            if (fr == 0) atomicAdd(&den[R], d_);
        }
        __syncthreads();
        // prod = w @ KV ; divide ; store
        f32x4 p0 = mm16(PAh, PAl, KVh, KVl, arow, brow, kg, z4());
#pragma unroll
        for (int m = 0; m < 4; ++m) {
            const int R = Rb + m;
            const float inv = 1.0f / (den[R] + 1e-12f);
            og[(size_t)((tt << 6) + R) * 64 + C] = p0[m] * inv;
        }
        __syncthreads();
    }
}

extern "C" void kernel_launch(void* const* d_in, const int* in_sizes, int n_in,
                              void* d_out, int out_size, void* d_ws, size_t ws_size,
                              hipStream_t stream) {
    const float* q = (const float*)d_in[0];
    const float* k = (const float*)d_in[1];
    const float* v = (const float*)d_in[2];
    float* out = (float*)d_out;
    float* ws  = (float*)d_ws;
    (void)in_sizes; (void)n_in; (void)out_size; (void)ws_size;

    hipFuncSetAttribute((const void*)k_main,
                        hipFuncAttributeMaxDynamicSharedMemorySize, SMEM_BYTES);

    k_init<<<1, 64, 0, stream>>>(ws);
    k_reduce<<<G_TOT, TPB_R, 0, stream>>>(q, k, ws);
    k_main<<<G_TOT, TPB_M, SMEM_BYTES, stream>>>(q, k, v, ws, out);
}

// Round 7
// 768.507 us; speedup vs baseline: 3.6965x; 1.1828x over previous
//
#include <hip/hip_runtime.h>
#include <math.h>

// PnPNystra attention, MFMA v5: 1024-thr / 16-wave k_main, barrier-thinned
// phase chain + register-cached fragments + buffer-rotation (16 LDS planes).
// G=4096 groups (B*H), N=256, d=64, L=64.
// All 64x64 matrices in LDS as SPLIT f16: v ~= h + l/2048 (lo pre-scaled by
// 2048 -> f16 normal range). Matmul = 3x mfma_f32_16x16x32_f16 (hh, h*l, l*h),
// fp32 accumulate -> ~2^-21 product error. Z (NS iterate) scaled by 1024.

#define G_TOT 4096
#define TPB_R 256
#define TPB_M 1024
typedef _Float16 f16;
typedef __attribute__((ext_vector_type(2))) _Float16 f16x2;
typedef __attribute__((ext_vector_type(4))) _Float16 f16x4;
typedef __attribute__((ext_vector_type(8))) _Float16 f16x8;
typedef __attribute__((ext_vector_type(4))) float f32x4;
typedef __attribute__((ext_vector_type(16))) float f32x16;

#define NPLANES 16
#define SMEM_BYTES (NPLANES * 4096 * 2 + 320 * 4)  // 132352 B

#define LSCALE 2048.0f
#define LINV   (1.0f / 2048.0f)
#define ZS     1024.0f
#define ZINV   (1.0f / 1024.0f)

struct HL { f16 h, l; };
__device__ __forceinline__ HL split2(float v) {
    HL r;
    r.h = (f16)v;
    r.l = (f16)((v - (float)r.h) * LSCALE);
    return r;
}
__device__ __forceinline__ float join2(f16 h, f16 l) {
    return (float)h + (float)l * LINV;
}
__device__ __forceinline__ int swi(int r, int c) {
    return (r << 6) + (c ^ ((r & 7) << 3));
}
__device__ __forceinline__ float activ_f(float x) {          // k_main fast path
    return __expf(fminf(x, 5.0f)) + fmaxf(x - 5.0f, 0.0f);
}
__device__ __forceinline__ float activ_r(float x) {          // k_reduce (unchanged)
    return expf(fminf(x, 5.0f)) + fmaxf(x - 5.0f, 0.0f);
}
__device__ __forceinline__ void split_w(f16* Ph, f16* Pl, int r, int c, float v) {
    HL s = split2(v);
    const int o = swi(r, c);
    Ph[o] = s.h;
    Pl[o] = s.l;
}
__device__ __forceinline__ f16x2 mk2(f16 a, f16 b) { f16x2 r; r[0]=a; r[1]=b; return r; }
__device__ __forceinline__ f16x4 mk4(f16 a, f16 b, f16 c, f16 d) { f16x4 r; r[0]=a;r[1]=b;r[2]=c;r[3]=d; return r; }
__device__ __forceinline__ f32x4 z4() { f32x4 z = {0.f,0.f,0.f,0.f}; return z; }
__device__ __forceinline__ f32x16 z16() {
    f32x16 z;
#pragma unroll
    for (int i = 0; i < 16; ++i) z[i] = 0.f;
    return z;
}

// ---- fragment container: one 16-row operand stripe for 16x16x32 MFMA ----
struct Frag { f16x8 h[2], l[2]; };

__device__ __forceinline__ Frag ld_frag(const f16* __restrict__ Ph,
                                        const f16* __restrict__ Pl,
                                        int row, int kg) {
    Frag f;
    const int base = row << 6, x = (row & 7) << 3;
#pragma unroll
    for (int s = 0; s < 2; ++s) {
        const int o = base + ((((s << 5) + (kg << 3))) ^ x);
        f.h[s] = *(const f16x8*)(Ph + o);
        f.l[s] = *(const f16x8*)(Pl + o);
    }
    return f;
}

// C_tile += A*B, 3-term split, both operands as register fragments.
__device__ __forceinline__ f32x4 mm16_rr(const Frag& A, const Frag& B, f32x4 acc) {
    f32x4 ax1 = z4(), ax2 = z4();
#pragma unroll
    for (int s = 0; s < 2; ++s) {
        acc = __builtin_amdgcn_mfma_f32_16x16x32_f16(A.h[s], B.h[s], acc, 0, 0, 0);
        ax1 = __builtin_amdgcn_mfma_f32_16x16x32_f16(A.h[s], B.l[s], ax1, 0, 0, 0);
        ax2 = __builtin_amdgcn_mfma_f32_16x16x32_f16(A.l[s], B.h[s], ax2, 0, 0, 0);
    }
    acc += (ax1 + ax2) * LINV;
    return acc;
}

// fragment writes: values v[m] live at (Rb+m, C)
__device__ __forceinline__ void wfrag_rm(f16* Ph, f16* Pl, int Rb, int C, const float* v) {
#pragma unroll
    for (int m = 0; m < 4; ++m) split_w(Ph, Pl, Rb + m, C, v[m]);
}
// transposed-layout write: plane[C][Rb..Rb+3] <- v[0..3]  (contiguous under swizzle)
__device__ __forceinline__ void wfrag_t(f16* Ph, f16* Pl, int Rb, int C, const float* v) {
    const int o = swi(C, Rb);
    HL s0 = split2(v[0]), s1 = split2(v[1]), s2 = split2(v[2]), s3 = split2(v[3]);
    *(f16x4*)(Ph + o) = mk4(s0.h, s1.h, s2.h, s3.h);
    *(f16x4*)(Pl + o) = mk4(s0.l, s1.l, s2.l, s3.l);
}

// ---- staging helpers (1024 threads) ----
__device__ __forceinline__ void wr_rm(float4 vv, f16* Ph, f16* Pl, int t) {
    const int r = t >> 4, c4 = (t & 15) << 2;
    const int o = swi(r, c4);
    HL s0 = split2(vv.x), s1 = split2(vv.y), s2 = split2(vv.z), s3 = split2(vv.w);
    *(f16x4*)(Ph + o) = mk4(s0.h, s1.h, s2.h, s3.h);
    *(f16x4*)(Pl + o) = mk4(s0.l, s1.l, s2.l, s3.l);
}
__device__ __forceinline__ void ld_vt(const float* __restrict__ src, int t,
                                      float2& va, float2& vb) {
    const int n0 = (t >> 5) << 1, e0 = (t & 31) << 1;
    va = *(const float2*)(src + (size_t)n0 * 64 + e0);
    vb = *(const float2*)(src + (size_t)(n0 + 1) * 64 + e0);
}
__device__ __forceinline__ void wr_vt(float2 va, float2 vb, f16* Ph, f16* Pl, int t) {
    const int n0 = (t >> 5) << 1, e0 = (t & 31) << 1;
    HL ax = split2(va.x), ay = split2(va.y), bx = split2(vb.x), by = split2(vb.y);
    const int o0 = swi(e0, n0), o1 = swi(e0 + 1, n0);
    *(f16x2*)(Ph + o0) = mk2(ax.h, bx.h);
    *(f16x2*)(Pl + o0) = mk2(ax.l, bx.l);
    *(f16x2*)(Ph + o1) = mk2(ay.h, by.h);
    *(f16x2*)(Pl + o1) = mk2(ay.l, by.l);
}

// pool 2x2-mean landmarks from global fp32 [256][64] -> split planes [64][64]
__device__ __forceinline__ void pool_global1024(const float* __restrict__ src,
                                                f16* Ph, f16* Pl, int t) {
    const int L = t >> 4, d0 = (t & 15) << 2;
    const int nb = ((L >> 3) << 5) + ((L & 7) << 1);
    const float* p = src + (size_t)nb * 64 + d0;
    float4 a = *(const float4*)p;
    float4 b = *(const float4*)(p + 64);
    float4 c = *(const float4*)(p + 1024);
    float4 d = *(const float4*)(p + 1088);
    HL s0 = split2(0.25f * (a.x + b.x + c.x + d.x));
    HL s1 = split2(0.25f * (a.y + b.y + c.y + d.y));
    HL s2 = split2(0.25f * (a.z + b.z + c.z + d.z));
    HL s3 = split2(0.25f * (a.w + b.w + c.w + d.w));
    const int o = swi(L, d0);
    *(f16x4*)(Ph + o) = mk4(s0.h, s1.h, s2.h, s3.h);
    *(f16x4*)(Pl + o) = mk4(s0.l, s1.l, s2.l, s3.l);
}

// pool landmarks of one staged K tile (tile tt) into KM planes (first 512 threads)
__device__ __forceinline__ void pool_lds512(const f16* Kh, const f16* Kl,
                                            f16* Ph, f16* Pl, int t, int tt) {
    const int ll = t >> 5, d0 = (t & 31) << 1;
    const int rb = ((ll >> 3) << 5) + ((ll & 7) << 1);
    float s0 = 0.f, s1 = 0.f;
#pragma unroll
    for (int rr = 0; rr < 4; ++rr) {
        const int r = rb + (rr & 1) + ((rr >> 1) << 4);
        const int o = swi(r, d0);
        f16x2 h = *(const f16x2*)(Kh + o);
        f16x2 l = *(const f16x2*)(Kl + o);
        s0 += join2(h[0], l[0]);
        s1 += join2(h[1], l[1]);
    }
    const int L = (tt << 4) + ll;
    HL p0 = split2(0.25f * s0), p1 = split2(0.25f * s1);
    const int o = swi(L, d0);
    *(f16x2*)(Ph + o) = mk2(p0.h, p1.h);
    *(f16x2*)(Pl + o) = mk2(p0.l, p1.l);
}

// ---- k_reduce helpers (unchanged from v3/v4) ----
__device__ __forceinline__ f32x16 mm64q(const f16* __restrict__ Ah, const f16* __restrict__ Al,
                                        const f16* __restrict__ Bh, const f16* __restrict__ Bl,
                                        int lane, int wr, int wc, f32x16 acc) {
    const int cl = lane & 31, hh = lane >> 5;
    const int ar = (wr << 5) + cl, br = (wc << 5) + cl;
    const int abase = ar << 6, axor = (ar & 7) << 3;
    const int bbase = br << 6, bxor = (br & 7) << 3;
    f32x16 ax1 = z16();
    f32x16 ax2 = z16();
#pragma unroll
    for (int ks = 0; ks < 4; ++ks) {
        const int k0 = (ks << 4) + (hh << 3);
        const int ao = abase + (k0 ^ axor);
        const int bo = bbase + (k0 ^ bxor);
        f16x8 a_h = *(const f16x8*)(Ah + ao);
        f16x8 a_l = *(const f16x8*)(Al + ao);
        f16x8 b_h = *(const f16x8*)(Bh + bo);
        f16x8 b_l = *(const f16x8*)(Bl + bo);
        acc = __builtin_amdgcn_mfma_f32_32x32x16_f16(a_h, b_h, acc, 0, 0, 0);
        ax1 = __builtin_amdgcn_mfma_f32_32x32x16_f16(a_h, b_l, ax1, 0, 0, 0);
        ax2 = __builtin_amdgcn_mfma_f32_32x32x16_f16(a_l, b_h, ax2, 0, 0, 0);
    }
    acc += (ax1 + ax2) * LINV;
    return acc;
}
__device__ __forceinline__ void pool_global_r(const float* __restrict__ src,
                                              f16* Ph, f16* Pl, int t) {
    const int ll = t >> 4, d0 = (t & 15) << 2;
    const int rb = ((ll >> 3) << 5) + ((ll & 7) << 1);
#pragma unroll
    for (int tt = 0; tt < 4; ++tt) {
        const float* p = src + (size_t)((tt << 6) + rb) * 64 + d0;
        float4 a = *(const float4*)p;
        float4 b = *(const float4*)(p + 64);
        float4 c = *(const float4*)(p + 1024);
        float4 d = *(const float4*)(p + 1088);
        const int L = (tt << 4) + ll;
        split_w(Ph, Pl, L, d0 + 0, 0.25f * (a.x + b.x + c.x + d.x));
        split_w(Ph, Pl, L, d0 + 1, 0.25f * (a.y + b.y + c.y + d.y));
        split_w(Ph, Pl, L, d0 + 2, 0.25f * (a.z + b.z + c.z + d.z));
        split_w(Ph, Pl, L, d0 + 3, 0.25f * (a.w + b.w + c.w + d.w));
    }
}

#define WAVE_SUM32(v)            \
    v += __shfl_xor(v, 1);       \
    v += __shfl_xor(v, 2);       \
    v += __shfl_xor(v, 4);       \
    v += __shfl_xor(v, 8);       \
    v += __shfl_xor(v, 16);

__global__ void k_init(float* ws) {
    if (threadIdx.x < 2) ws[threadIdx.x] = 0.0f;
}

// global max of row/col sums of activ(QM @ KM^T) over all groups (unchanged)
__global__ __launch_bounds__(TPB_R) void k_reduce(const float* __restrict__ q,
                                                  const float* __restrict__ k,
                                                  float* __restrict__ ws) {
    __shared__ f16 pls[4 * 4096];
    __shared__ float rowS[64], colS[64];
    const int t = threadIdx.x, g = blockIdx.x;
    const int lane = t & 63, wv = t >> 6, wr = wv >> 1, wc = wv & 1;
    const int cl = lane & 31, hh = lane >> 5;
    if (t < 64) rowS[t] = 0.f;
    else if (t < 128) colS[t - 64] = 0.f;
    pool_global_r(q + (size_t)g * 16384, pls, pls + 4096, t);
    pool_global_r(k + (size_t)g * 16384, pls + 8192, pls + 12288, t);
    __syncthreads();
    f32x16 a = mm64q(pls, pls + 4096, pls + 8192, pls + 12288, lane, wr, wc, z16());
    float colp = 0.f;
#pragma unroll
    for (int m = 0; m < 16; ++m) {
        float x = activ_r(a[m]);
        const int R = (wr << 5) + (m & 3) + ((m >> 2) << 3) + (hh << 2);
        float vs = x;
        WAVE_SUM32(vs)
        if (cl == 0) atomicAdd(&rowS[R], vs);
        colp += x;
    }
    colp += __shfl_xor(colp, 32);
    if (hh == 0) atomicAdd(&colS[(wc << 5) + cl], colp);
    __syncthreads();
    if (t < 64) {
        float vmx = rowS[t];
        for (int off = 1; off < 64; off <<= 1) vmx = fmaxf(vmx, __shfl_xor(vmx, off));
        if (t == 0) atomicMax((int*)ws, __float_as_int(vmx));
    } else if (t < 128) {
        float vmx = colS[t - 64];
        for (int off = 1; off < 64; off <<= 1) vmx = fmaxf(vmx, __shfl_xor(vmx, off));
        if (t == 64) atomicMax(((int*)ws) + 1, __float_as_int(vmx));
    }
}

// ============================ k_main (v5) ============================
// Plane schedule (pairs of 4096-f16 planes):
//  (0,1)  Xh/Xl : Vt-pong (E) -> X (B, reg-cached at D start) -> T2 (D)
//  (2,3)  SA    : Kst (E) -> T1rm/Znew-rm gen-slot (D) -> qst (F)
//  (4,5)  SB    : Vt-ping (E) -> oT (D) -> w (F)
//  (6,7)  KM    : persistent E -> B -> F
//  (8,9)  SC    : S (E) -> T1t/Znew-t gen-slot (D) -> qk (F)
//  (10,11)KV    : persistent (written end of E/B, read F)
//  (12,13)Z0r   : QM (A/E, reg-cached) -> Zr (B, D even-gens, final)
//  (14,15)Z0t   : Zt (B, D even-gens, final; B-operand in F)
__global__ __launch_bounds__(TPB_M, 4) void k_main(const float* __restrict__ q,
                                                   const float* __restrict__ k,
                                                   const float* __restrict__ v,
                                                   const float* __restrict__ ws,
                                                   float* __restrict__ out) {
    extern __shared__ f16 smu[];
    float* kv1 = (float*)(smu + NPLANES * 4096);
    float* den = kv1 + 64;  // den[4][64]
    const int t = threadIdx.x, g = blockIdx.x;
    const int lane = t & 63, w = t >> 6;
    const int ti = w & 3, tj = w >> 2;
    const int fr = lane & 15, kg = lane >> 4;
    const int arow = (ti << 4) + fr;
    const int brow = (tj << 4) + fr;
    const int C = brow;
    const int Rb = (ti << 4) + (kg << 2);
    const float* Gq = q + (size_t)g * 16384;
    const float* Gk = k + (size_t)g * 16384;
    const float* Gv = v + (size_t)g * 16384;
    float* og = out + (size_t)g * 16384;

    f16* Xh  = smu +  0 * 4096; f16* Xl  = smu +  1 * 4096;
    f16* SAh = smu +  2 * 4096; f16* SAl = smu +  3 * 4096;
    f16* SBh = smu +  4 * 4096; f16* SBl = smu +  5 * 4096;
    f16* KMh = smu +  6 * 4096; f16* KMl = smu +  7 * 4096;
    f16* SCh = smu +  8 * 4096; f16* SCl = smu +  9 * 4096;
    f16* KVh = smu + 10 * 4096; f16* KVl = smu + 11 * 4096;
    f16* Z0rh= smu + 12 * 4096; f16* Z0rl= smu + 13 * 4096;
    f16* Z0th= smu + 14 * 4096; f16* Z0tl= smu + 15 * 4096;

    // ---- prologue: pool QM -> (12,13); stage K0 -> SA, V0^T -> SB; zero sums ----
    if (t < 320) kv1[t] = 0.f;                 // kv1[64] + den[4][64]
    pool_global1024(Gq, Z0rh, Z0rl, t);
    {
        float4 kreg = *(const float4*)(Gk + (size_t)t * 4);
        float2 va, vb; ld_vt(Gv, t, va, vb);
        wr_rm(kreg, SAh, SAl, t);
        wr_vt(va, vb, SBh, SBl, t);
    }
    __syncthreads();

    // cache QM A-fragments (QM LDS is dead after this phase's barrier)
    Frag fQM = ld_frag(Z0rh, Z0rl, arow, kg);

    // ---- phase E: KV = activ(QM @ K^T) @ V ; pool KM; kv1 row sums ----
    f32x4 kva = z4();
    for (int tt = 0; tt < 4; ++tt) {
        f16* vch = (tt & 1) ? Xh : SBh;  f16* vcl = (tt & 1) ? Xl : SBl;   // Vt cur
        f16* vnh = (tt & 1) ? SBh : Xh;  f16* vnl = (tt & 1) ? SBl : Xl;   // Vt next
        float4 kregN; float2 vaN, vbN;
        if (tt < 3) {
            kregN = *(const float4*)(Gk + (size_t)(tt + 1) * 4096 + (size_t)t * 4);
            ld_vt(Gv + (size_t)(tt + 1) * 4096, t, vaN, vbN);
        }
        // e2: pool KM from staged K; S = activ(QM@K^T); kv1; stage next V^T
        if (t < 512) pool_lds512(SAh, SAl, KMh, KMl, t, tt);
        {
            Frag bK = ld_frag(SAh, SAl, brow, kg);
            f32x4 s = mm16_rr(fQM, bK, z4());
            float sv[4];
#pragma unroll
            for (int m = 0; m < 4; ++m) {
                sv[m] = activ_f(s[m]);
                float vs = sv[m];
                vs += __shfl_xor(vs, 1); vs += __shfl_xor(vs, 2);
                vs += __shfl_xor(vs, 4); vs += __shfl_xor(vs, 8);
                if (fr == 0) atomicAdd(&kv1[Rb + m], vs);
            }
            wfrag_rm(SCh, SCl, Rb, C, sv);
        }
        if (tt < 3) wr_vt(vaN, vbN, vnh, vnl, t);
        __syncthreads();
        // e3: KV += S @ V ; stage next K
        {
            Frag aS = ld_frag(SCh, SCl, arow, kg);
            Frag bV = ld_frag(vch, vcl, brow, kg);
            kva = mm16_rr(aS, bV, kva);
        }
        if (tt < 3) wr_rm(kregN, SAh, SAl, t);
        __syncthreads();
    }

    // ---- phase B: KV store (T-layout); X = activ(QM@KM^T); Z-init (fused C) ----
    {
        float kvv[4] = {kva[0], kva[1], kva[2], kva[3]};
        wfrag_t(KVh, KVl, Rb, C, kvv);
        Frag fKMb = ld_frag(KMh, KMl, brow, kg);
        f32x4 x0 = mm16_rr(fQM, fKMb, z4());
        const float scale = ZS / (ws[0] * ws[1] + 1e-15f);
        float xv[4], zv[4];
#pragma unroll
        for (int m = 0; m < 4; ++m) { xv[m] = activ_f(x0[m]); zv[m] = xv[m] * scale; }
        wfrag_rm(Xh, Xl, Rb, C, xv);       // X row-major
        wfrag_t (Z0rh, Z0rl, Rb, C, zv);   // Zr[c][r] = scale*X[r][c]   (Z row-major)
        wfrag_rm(Z0th, Z0tl, Rb, C, zv);   // Zt[r][c] = scale*X[r][c]   (Z^T, B-layout)
    }
    __syncthreads();

    // ---- phase D: 6 Newton-Schulz iterations, gen ping-pong, 4 barriers/iter ----
    Frag fX = ld_frag(Xh, Xl, arow, kg);   // X-as-A, reused all 6 iters
    f16 *zrh = Z0rh, *zrl = Z0rl, *zth = Z0th, *ztl = Z0tl;   // current Z
    f16 *nrh = SAh,  *nrl = SAl,  *nth = SCh,  *ntl = SCl;    // T1 slots -> next Z
#pragma unroll
    for (int it = 0; it < 6; ++it) {
        // T1 = X @ Z  (acc carries ZS)
        Frag bz = ld_frag(zth, ztl, brow, kg);
        f32x4 a1 = mm16_rr(fX, bz, z4());
        float t1k[4];
#pragma unroll
        for (int m = 0; m < 4; ++m) t1k[m] = a1[m] * ZINV;
        wfrag_rm(nrh, nrl, Rb, C, t1k);
        wfrag_t (nth, ntl, Rb, C, t1k);
        __syncthreads();
        // T2 = T1 @ T1  (cache T1^T B-frag for T4)
        Frag aT1 = ld_frag(nrh, nrl, arow, kg);
        Frag bT1 = ld_frag(nth, ntl, brow, kg);
        f32x4 a2 = mm16_rr(aT1, bT1, z4());
        float t2k[4];
#pragma unroll
        for (int m = 0; m < 4; ++m) t2k[m] = a2[m];
        wfrag_rm(Xh, Xl, Rb, C, t2k);      // T2 -> (0,1) (X LDS dead, fX in regs)
        __syncthreads();
        // T4 = T2 @ T1 ; outer = 13I - 15 T1 + 7 T2 - T4 (own frags in regs)
        Frag aT2 = ld_frag(Xh, Xl, arow, kg);
        f32x4 a3 = mm16_rr(aT2, bT1, z4());
        float ov[4];
#pragma unroll
        for (int m = 0; m < 4; ++m) {
            const int R = Rb + m;
            ov[m] = ((R == C) ? 13.f : 0.f) - 15.f * t1k[m] + 7.f * t2k[m] - a3[m];
        }
        wfrag_t(SBh, SBl, Rb, C, ov);      // oT -> (4,5)
        __syncthreads();
        // Znew = 0.25 * Z @ outer  (writes into dead T1 slots -> next gen)
        Frag aZ = ld_frag(zrh, zrl, arow, kg);
        Frag bO = ld_frag(SBh, SBl, brow, kg);
        f32x4 a4 = mm16_rr(aZ, bO, z4());
        float zk[4];
#pragma unroll
        for (int m = 0; m < 4; ++m) zk[m] = 0.25f * a4[m];
        wfrag_rm(nrh, nrl, Rb, C, zk);
        wfrag_t (nth, ntl, Rb, C, zk);
        __syncthreads();
        // swap generations
        f16* tp;
        tp = zrh; zrh = nrh; nrh = tp;  tp = zrl; zrl = nrl; nrl = tp;
        tp = zth; zth = nth; nth = tp;  tp = ztl; ztl = ntl; ntl = tp;
    }
    // after 6 iters (even), final Z is back in Z0 planes: Zr=(12,13), Zt=(14,15)

    // ---- phase F: out = (activ(q@KM^T) @ Z @ KV) / den ----
    Frag fKM = ld_frag(KMh, KMl, brow, kg);    // B for qk-mm, reused 4x
    Frag fZt = ld_frag(Z0th, Z0tl, brow, kg);  // B for w-mm
    Frag fKV = ld_frag(KVh, KVl, brow, kg);    // B for prod-mm
    const float kvC = kv1[C];
    {
        float4 qreg = *(const float4*)(Gq + (size_t)t * 4);
        wr_rm(qreg, SAh, SAl, t);
    }
    __syncthreads();
    for (int tt = 0; tt < 4; ++tt) {
        float4 qregN;
        if (tt < 3) qregN = *(const float4*)(Gq + (size_t)(tt + 1) * 4096 + (size_t)t * 4);
        // f2: qk = activ(q @ KM^T)
        {
            Frag aQ = ld_frag(SAh, SAl, arow, kg);
            f32x4 q0 = mm16_rr(aQ, fKM, z4());
            float qv[4];
#pragma unroll
            for (int m = 0; m < 4; ++m) qv[m] = activ_f(q0[m]);
            wfrag_rm(SCh, SCl, Rb, C, qv);
        }
        __syncthreads();
        // f3: w = qk @ Z ; den
        float* dn = den + (tt << 6);
        {
            Frag aK = ld_frag(SCh, SCl, arow, kg);
            f32x4 w0 = mm16_rr(aK, fZt, z4());
            float wv[4];
#pragma unroll
            for (int m = 0; m < 4; ++m) {
                wv[m] = w0[m] * ZINV;
                float d_ = wv[m] * kvC;
                d_ += __shfl_xor(d_, 1); d_ += __shfl_xor(d_, 2);
                d_ += __shfl_xor(d_, 4); d_ += __shfl_xor(d_, 8);
                if (fr == 0) atomicAdd(&dn[Rb + m], d_);
            }
            wfrag_rm(SBh, SBl, Rb, C, wv);
        }
        __syncthreads();
        // f4: prod = w @ KV ; divide ; store ; stage next q
        {
            Frag aW = ld_frag(SBh, SBl, arow, kg);
            f32x4 p0 = mm16_rr(aW, fKV, z4());
#pragma unroll
            for (int m = 0; m < 4; ++m) {
                const int R = Rb + m;
                const float inv = 1.0f / (dn[R] + 1e-12f);
                og[(size_t)((tt << 6) + R) * 64 + C] = p0[m] * inv;
            }
        }
        if (tt < 3) wr_rm(qregN, SAh, SAl, t);
        __syncthreads();
    }
}

extern "C" void kernel_launch(void* const* d_in, const int* in_sizes, int n_in,
                              void* d_out, int out_size, void* d_ws, size_t ws_size,
                              hipStream_t stream) {
    const float* q = (const float*)d_in[0];
    const float* k = (const float*)d_in[1];
    const float* v = (const float*)d_in[2];
    float* out = (float*)d_out;
    float* ws  = (float*)d_ws;
    (void)in_sizes; (void)n_in; (void)out_size; (void)ws_size;

    hipFuncSetAttribute((const void*)k_main,
                        hipFuncAttributeMaxDynamicSharedMemorySize, SMEM_BYTES);

    k_init<<<1, 64, 0, stream>>>(ws);
    k_reduce<<<G_TOT, TPB_R, 0, stream>>>(q, k, ws);
    k_main<<<G_TOT, TPB_M, SMEM_BYTES, stream>>>(q, k, v, ws, out);
}